// Round 12
// baseline (40681.860 us; speedup 1.0000x reference)
//
#include <hip/hip_runtime.h>
#include <hip/hip_bf16.h>

// IPM QP solver, f64, dispatch/stage-count optimized.
// Constant precompute (verified): Q, chol(Q), Qi, K0inv blocks (XX,XY,SAi),
// FK0x=G*XX, FK0y=G*XY, S=FK0x*G^T, transposes.
// Per iteration, 8 dispatches:
//  A1: rx, rp(+uv,dinv), ry, M=S+diag(s/z)
//  A2: rhs1, g0 -> Mm row 512, diag0(M)->DGC[0]
//  k_fps2 x3 + tail: TWO chol steps per dispatch (panels recomputed on the fly,
//     S11 factored redundantly per block; boss emits DG[kb+1],DG[kb+2],PL cols)
//  bwdupd: fwd strips + backward solve + ds/dz/alpha + s,z,mu update
//  C : dx,dy rows (precomputed GEMV) + x,y update
// Output x as f32.

constexpr int ND = 1024;
constexpr int MI = 512;
constexpr int PE = 256;
constexpr int NM = 512;      // per-iter Schur dim
constexpr int LDM = 520;
constexpr double EPSQ = 1e-4;
constexpr double SIG = 0.1;
constexpr int NITER = 25;

__device__ __forceinline__ double wred(double v) {
#pragma unroll
  for (int off = 32; off; off >>= 1) v += __shfl_down(v, off, 64);
  return v;
}

// ---------------- setup ----------------
__global__ void k_prep(const float* __restrict__ Gf, const float* __restrict__ Af,
                       const float* __restrict__ qf, const float* __restrict__ bf,
                       float* __restrict__ GTf, float* __restrict__ ATf,
                       double* __restrict__ qd, double* __restrict__ bd,
                       double* __restrict__ xv, double* __restrict__ sv,
                       double* __restrict__ zv, double* __restrict__ yv,
                       double* __restrict__ scal) {
  if (blockIdx.x == 0 && threadIdx.x == 0) { scal[0] = 1.0; scal[1] = 0.0; }
  for (size_t idx = (size_t)blockIdx.x * blockDim.x + threadIdx.x;
       idx < (size_t)MI * ND; idx += (size_t)gridDim.x * blockDim.x) {
    int k = (int)(idx >> 10), i = (int)(idx & 1023);
    GTf[(size_t)i * MI + k] = Gf[idx];
    if (idx < (size_t)PE * ND) ATf[(size_t)i * PE + k] = Af[idx];
    if (idx < ND) { qd[idx] = (double)qf[idx]; xv[idx] = 0.0; }
    if (idx < MI) { sv[idx] = 1.0; zv[idx] = 1.0; }
    if (idx < PE) { bd[idx] = (double)bf[idx]; yv[idx] = 0.0; }
  }
}

__global__ __launch_bounds__(256) void k_h(const float* __restrict__ Gf,
                                           const float* __restrict__ x0f,
                                           const float* __restrict__ s0f,
                                           double* __restrict__ hd) {
  int wid = blockIdx.x * 4 + (int)(threadIdx.x >> 6), lane = threadIdx.x & 63;
  if (wid >= MI) return;
  double acc = 0;
  for (int c = lane; c < ND; c += 64) acc += (double)Gf[(size_t)wid * ND + c] * (double)x0f[c];
  acc = wred(acc);
  if (lane == 0) hd[wid] = acc + (double)s0f[wid];
}

__global__ __launch_bounds__(256) void k_qbuild(const float* __restrict__ Lf,
                                                double* __restrict__ Qd, double* __restrict__ LQ) {
  __shared__ double As[32][33], Bs[32][33];
  int i0 = blockIdx.y * 32, j0 = blockIdx.x * 32;
  int tx = threadIdx.x & 15, ty = threadIdx.x >> 4;
  double acc[2][2] = {};
  int kmax = (i0 < j0 ? i0 : j0) + 32;
  for (int k0 = 0; k0 < kmax; k0 += 32) {
    for (int l = threadIdx.x; l < 1024; l += 256) {
      int r = l >> 5, c = l & 31;
      As[r][c] = (k0 + c <= i0 + r) ? (double)Lf[(size_t)(i0 + r) * ND + k0 + c] : 0.0;
      Bs[r][c] = (k0 + c <= j0 + r) ? (double)Lf[(size_t)(j0 + r) * ND + k0 + c] : 0.0;
    }
    __syncthreads();
#pragma unroll
    for (int k = 0; k < 32; k++) {
      double a0 = As[2 * ty][k], a1 = As[2 * ty + 1][k];
      double b0 = Bs[2 * tx][k], b1 = Bs[2 * tx + 1][k];
      acc[0][0] += a0 * b0; acc[0][1] += a0 * b1;
      acc[1][0] += a1 * b0; acc[1][1] += a1 * b1;
    }
    __syncthreads();
  }
  for (int da = 0; da < 2; da++)
    for (int db = 0; db < 2; db++) {
      int i = i0 + 2 * ty + da, j = j0 + 2 * tx + db;
      double v = acc[da][db] + (i == j ? EPSQ : 0.0);
      Qd[(size_t)i * ND + j] = v;
      LQ[(size_t)i * ND + j] = v;
    }
}

// diag0: factor A(kb,kb) + write DG[kb]  (verified)
__global__ __launch_bounds__(256) void k_chol_diag_inv(double* __restrict__ A, int lda, int kb,
                                                       double* __restrict__ DG) {
  __shared__ double a[64][65];
  __shared__ double invp[2080];
  __shared__ double dfloor;
  int t = threadIdx.x;
  size_t base = (size_t)kb * 64;
  for (int l = t; l < 4096; l += 256) { int r = l >> 6, c = l & 63; a[r][c] = A[(base + r) * lda + base + c]; }
  __syncthreads();
  if (t == 0) {
    double m = 0;
    for (int i = 0; i < 64; i++) m = fmax(m, fabs(a[i][i]));
    dfloor = m * 1e-28 + 1e-280;
  }
  __syncthreads();
  for (int j = 0; j < 64; j++) {
    if (t == 0) a[j][j] = sqrt(fmax(a[j][j], dfloor));
    __syncthreads();
    double piv = a[j][j];
    for (int r = j + 1 + t; r < 64; r += 256) a[r][j] /= piv;
    __syncthreads();
    int w = 63 - j;
    for (int l = t; l < w * w; l += 256) {
      int rr = j + 1 + l / w, cc = j + 1 + l % w;
      if (cc <= rr) a[rr][cc] -= a[rr][j] * a[cc][j];
    }
    __syncthreads();
  }
  for (int l = t; l < 4096; l += 256) { int r = l >> 6, c = l & 63; if (c <= r) A[(base + r) * lda + base + c] = a[r][c]; }
  if (t < 64) {
    int c = t;
    for (int i = c; i < 64; i++) {
      double v = (i == c) ? 1.0 : 0.0;
      for (int k = c; k < i; k++) v -= a[i][k] * invp[k * (k + 1) / 2 + c];
      invp[i * (i + 1) / 2 + c] = v / a[i][i];
    }
  }
  __syncthreads();
  for (int l = t; l < 4096; l += 256) {
    int r = l >> 6, c = l & 63;
    DG[(size_t)kb * 4096 + (size_t)c * 64 + r] = (c <= r) ? invp[r * (r + 1) / 2 + c] : 0.0;
  }
}

// Fused DOUBLE chol step (kb, kb+1). Trailing blocks (i,j) with kb+2<=j<=i<nbk.
// Each block: C=A(kb+1,kb)*DT0; Pi0,Pj0; acc-=Pi0 Pj0^T; Ui,Uj; S11 factored
// locally -> DT1; Pi1,Pj1; acc-=Pi1 Pj1^T. Boss (block 0 = (kb+2,kb+2)) writes
// DG[kb+1], PL row kb+1 col kb, and factors its tile -> DG[kb+2].
// Tail mode (kb+2>=nbk): single block computes C, PL, DG[kb+1] only.
__global__ __launch_bounds__(256) void k_fps2(double* __restrict__ A, int lda,
                                              double* __restrict__ PL, int ldp,
                                              double* __restrict__ DG, int kb, int nbk) {
  extern __shared__ double sh[];
  double* D  = sh;           // 4160: DT0 -> 'a'/DT1 -> boss 'a'
  double* Cb = sh + 4160;    // 4160: C; later invp overlay
  double* Pb = sh + 8320;    // 4160: Pi0 -> Ui -> Pi1
  double* Lb = sh + 12480;   // 4160: load buf / Pj0 -> Uj -> Pj1
  const int t = threadIdx.x, tx = t & 15, ty = t >> 4;
  const bool tail = (kb + 2 >= nbk);
  int bi = 0, bj = 0;
  if (!tail) {
    int idx = blockIdx.x;
    bi = (int)((sqrtf(8.0f * (float)idx + 1.0f) - 1.0f) * 0.5f);
    while ((bi + 1) * (bi + 2) / 2 <= idx) ++bi;
    while (bi * (bi + 1) / 2 > idx) --bi;
    bj = idx - bi * (bi + 1) / 2;
  }
  const int ib = kb + 2 + bi, jb = kb + 2 + bj;
  const bool isDiag = (ib == jb);
  const bool isBoss = (blockIdx.x == 0);

  double tmp[4][4];
  auto loadTile = [&](double* dst, int rb, int cb) {
    for (int l = t; l < 4096; l += 256) {
      int r = l >> 6, c = l & 63;
      dst[r * 65 + c] = A[(size_t)(rb * 64 + r) * lda + cb * 64 + c];
    }
  };
  auto mulD = [&](const double* X) {  // tmp = X(65-pad) * D(DT layout) == X * Ldiag^{-T}
#pragma unroll
    for (int e = 0; e < 4; e++)
#pragma unroll
      for (int f = 0; f < 4; f++) tmp[e][f] = 0;
    for (int k = 0; k < 64; ++k) {
      double x0 = X[ty * 65 + k], x1 = X[(ty + 16) * 65 + k];
      double x2 = X[(ty + 32) * 65 + k], x3 = X[(ty + 48) * 65 + k];
      double d0 = D[k * 64 + tx], d1 = D[k * 64 + tx + 16];
      double d2 = D[k * 64 + tx + 32], d3 = D[k * 64 + tx + 48];
      tmp[0][0] += x0 * d0; tmp[0][1] += x0 * d1; tmp[0][2] += x0 * d2; tmp[0][3] += x0 * d3;
      tmp[1][0] += x1 * d0; tmp[1][1] += x1 * d1; tmp[1][2] += x1 * d2; tmp[1][3] += x1 * d3;
      tmp[2][0] += x2 * d0; tmp[2][1] += x2 * d1; tmp[2][2] += x2 * d2; tmp[2][3] += x2 * d3;
      tmp[3][0] += x3 * d0; tmp[3][1] += x3 * d1; tmp[3][2] += x3 * d2; tmp[3][3] += x3 * d3;
    }
  };
  auto mulNT = [&](const double* X, const double* Y) {  // tmp = X*Y^T (both 65-pad)
#pragma unroll
    for (int e = 0; e < 4; e++)
#pragma unroll
      for (int f = 0; f < 4; f++) tmp[e][f] = 0;
    for (int k = 0; k < 64; ++k) {
      double x0 = X[ty * 65 + k], x1 = X[(ty + 16) * 65 + k];
      double x2 = X[(ty + 32) * 65 + k], x3 = X[(ty + 48) * 65 + k];
      double y0 = Y[tx * 65 + k], y1 = Y[(tx + 16) * 65 + k];
      double y2 = Y[(tx + 32) * 65 + k], y3 = Y[(tx + 48) * 65 + k];
      tmp[0][0] += x0 * y0; tmp[0][1] += x0 * y1; tmp[0][2] += x0 * y2; tmp[0][3] += x0 * y3;
      tmp[1][0] += x1 * y0; tmp[1][1] += x1 * y1; tmp[1][2] += x1 * y2; tmp[1][3] += x1 * y3;
      tmp[2][0] += x2 * y0; tmp[2][1] += x2 * y1; tmp[2][2] += x2 * y2; tmp[2][3] += x2 * y3;
      tmp[3][0] += x3 * y0; tmp[3][1] += x3 * y1; tmp[3][2] += x3 * y2; tmp[3][3] += x3 * y3;
    }
  };
  auto storeTmp = [&](double* dst) {
    __syncthreads();
#pragma unroll
    for (int e = 0; e < 4; e++)
#pragma unroll
      for (int f = 0; f < 4; f++) dst[(ty + 16 * e) * 65 + tx + 16 * f] = tmp[e][f];
    __syncthreads();
  };
  // factor D ('a' 65-pad layout) -> rewrite D as DT layout; invp overlay in Cb.
  auto factorD = [&](int dgout) {
    if (t == 0) {
      double m = 0;
      for (int i2 = 0; i2 < 64; i2++) m = fmax(m, fabs(D[i2 * 65 + i2]));
      D[4159] = m * 1e-28 + 1e-280;
    }
    __syncthreads();
    double dfl = D[4159];
    for (int j = 0; j < 64; ++j) {
      if (t == 0) D[j * 65 + j] = sqrt(fmax(D[j * 65 + j], dfl));
      __syncthreads();
      double piv = D[j * 65 + j];
      for (int r = j + 1 + t; r < 64; r += 256) D[r * 65 + j] /= piv;
      __syncthreads();
      int w = 63 - j;
      for (int l = t; l < w * w; l += 256) {
        int rr = j + 1 + l / w, cc = j + 1 + l % w;
        if (cc <= rr) D[rr * 65 + cc] -= D[rr * 65 + j] * D[cc * 65 + j];
      }
      __syncthreads();
    }
    double* invp = Cb;
    if (t < 64) {
      int c = t;
      for (int i2 = c; i2 < 64; ++i2) {
        double v = (i2 == c) ? 1.0 : 0.0;
        for (int k = c; k < i2; ++k) v -= D[i2 * 65 + k] * invp[k * (k + 1) / 2 + c];
        invp[i2 * (i2 + 1) / 2 + c] = v / D[i2 * 65 + i2];
      }
    }
    __syncthreads();
    for (int l = t; l < 4096; l += 256) {
      int k = l >> 6, c = l & 63;
      D[k * 64 + c] = (k <= c) ? invp[c * (c + 1) / 2 + k] : 0.0;  // DT layout
    }
    __syncthreads();
    if (dgout >= 0 && isBoss)
      for (int l = t; l < 4096; l += 256) DG[(size_t)dgout * 4096 + l] = D[l];  // linear copy (layout identity)
    __syncthreads();
  };

  // ---- load DT0 ----
  for (int l = t; l < 4096; l += 256) D[l] = DG[(size_t)kb * 4096 + l];
  __syncthreads();

  if (tail) {
    loadTile(Lb, kb + 1, kb);
    __syncthreads();
    mulD(Lb); storeTmp(Cb);                       // C
    for (int l = t; l < 4096; l += 256) {
      int r = l >> 6, c = l & 63;
      PL[(size_t)((kb + 1) * 64 + r) * ldp + kb * 64 + c] = Cb[r * 65 + c];
    }
    mulNT(Cb, Cb);
    __syncthreads();
#pragma unroll
    for (int e = 0; e < 4; e++)
#pragma unroll
      for (int f = 0; f < 4; f++)
        D[(ty + 16 * e) * 65 + tx + 16 * f] =
            A[(size_t)((kb + 1) * 64 + ty + 16 * e) * lda + (kb + 1) * 64 + tx + 16 * f] - tmp[e][f];
    __syncthreads();
    factorD(kb + 1);
    return;
  }

  // ---- full mode ----
  double acc[4][4];
#pragma unroll
  for (int e = 0; e < 4; e++)
#pragma unroll
    for (int f = 0; f < 4; f++)
      acc[e][f] = A[(size_t)(ib * 64 + ty + 16 * e) * lda + jb * 64 + tx + 16 * f];

  // C
  loadTile(Lb, kb + 1, kb);
  __syncthreads();
  mulD(Lb); storeTmp(Cb);
  if (isBoss)
    for (int l = t; l < 4096; l += 256) {
      int r = l >> 6, c = l & 63;
      PL[(size_t)((kb + 1) * 64 + r) * ldp + kb * 64 + c] = Cb[r * 65 + c];
    }
  // Pi0
  loadTile(Lb, ib, kb);
  __syncthreads();
  mulD(Lb); storeTmp(Pb);
  if (isDiag)
    for (int l = t; l < 4096; l += 256) {
      int r = l >> 6, c = l & 63;
      PL[(size_t)(ib * 64 + r) * ldp + kb * 64 + c] = Pb[r * 65 + c];
    }
  // Pj0
  if (!isDiag) {
    loadTile(Lb, jb, kb);
    __syncthreads();
    mulD(Lb); storeTmp(Lb);
  }
  const double* Pj0 = isDiag ? Pb : Lb;
  mulNT(Pb, Pj0);
#pragma unroll
  for (int e = 0; e < 4; e++)
#pragma unroll
    for (int f = 0; f < 4; f++) acc[e][f] -= tmp[e][f];
  // Ui = A(i,kb+1) - Pi0*C^T  -> Pb
  mulNT(Pb, Cb);
#pragma unroll
  for (int e = 0; e < 4; e++)
#pragma unroll
    for (int f = 0; f < 4; f++)
      tmp[e][f] = A[(size_t)(ib * 64 + ty + 16 * e) * lda + (kb + 1) * 64 + tx + 16 * f] - tmp[e][f];
  storeTmp(Pb);
  // Uj -> Lb
  if (!isDiag) {
    mulNT(Lb, Cb);
#pragma unroll
    for (int e = 0; e < 4; e++)
#pragma unroll
      for (int f = 0; f < 4; f++)
        tmp[e][f] = A[(size_t)(jb * 64 + ty + 16 * e) * lda + (kb + 1) * 64 + tx + 16 * f] - tmp[e][f];
    storeTmp(Lb);
  }
  // S11 = A(kb+1,kb+1) - C*C^T -> D('a'); factor -> DT1 (+DG[kb+1] by boss). C dies here.
  mulNT(Cb, Cb);
  __syncthreads();
#pragma unroll
  for (int e = 0; e < 4; e++)
#pragma unroll
    for (int f = 0; f < 4; f++)
      D[(ty + 16 * e) * 65 + tx + 16 * f] =
          A[(size_t)((kb + 1) * 64 + ty + 16 * e) * lda + (kb + 1) * 64 + tx + 16 * f] - tmp[e][f];
  __syncthreads();
  factorD(kb + 1);
  // Pi1 = Ui*DT1 -> Pb
  mulD(Pb); storeTmp(Pb);
  if (isDiag)
    for (int l = t; l < 4096; l += 256) {
      int r = l >> 6, c = l & 63;
      PL[(size_t)(ib * 64 + r) * ldp + (kb + 1) * 64 + c] = Pb[r * 65 + c];
    }
  // Pj1 -> Lb
  if (!isDiag) { mulD(Lb); storeTmp(Lb); }
  const double* Pj1 = isDiag ? Pb : Lb;
  mulNT(Pb, Pj1);
#pragma unroll
  for (int e = 0; e < 4; e++)
#pragma unroll
    for (int f = 0; f < 4; f++) acc[e][f] -= tmp[e][f];

  if (isBoss) {
    // factor acc (= fully-updated A(kb+2,kb+2)) -> DG[kb+2]; do not write A.
    __syncthreads();
#pragma unroll
    for (int e = 0; e < 4; e++)
#pragma unroll
      for (int f = 0; f < 4; f++) D[(ty + 16 * e) * 65 + tx + 16 * f] = acc[e][f];
    __syncthreads();
    factorD(kb + 2);
  } else {
#pragma unroll
    for (int e = 0; e < 4; e++)
#pragma unroll
      for (int f = 0; f < 4; f++)
        A[(size_t)(ib * 64 + ty + 16 * e) * lda + jb * 64 + tx + 16 * f] = acc[e][f];
  }
}

// generic trsm identity-RHS fwd / in-place bwd (verified); L read from PL
__global__ __launch_bounds__(256) void k_trsmf_g(const double* __restrict__ Lm, int lda,
                                                 double* __restrict__ X, int ldx,
                                                 const double* __restrict__ DG, int kb) {
  __shared__ double Lb[64][64];
  __shared__ double Xs[64][33];
  int t = threadIdx.x;
  int c0 = blockIdx.x * 32;
  int lane2 = t & 31, rbase = t >> 5;
  int row0 = kb * 64;
  double acc[8];
#pragma unroll
  for (int e = 0; e < 8; e++) acc[e] = (row0 + rbase + 8 * e == c0 + lane2) ? 1.0 : 0.0;
  for (int jb = 0; jb < kb; jb++) {
    for (int l = t; l < 4096; l += 256) { int r = l >> 6, c = l & 63; Lb[r][c] = Lm[(size_t)(row0 + r) * lda + jb * 64 + c]; }
    for (int l = t; l < 2048; l += 256) { int k = l >> 5, c = l & 31; Xs[k][c] = X[(size_t)(jb * 64 + k) * ldx + c0 + c]; }
    __syncthreads();
#pragma unroll 4
    for (int k = 0; k < 64; k++) {
      double wv = Xs[k][lane2];
#pragma unroll
      for (int e = 0; e < 8; e++) acc[e] -= Lb[rbase + 8 * e][k] * wv;
    }
    __syncthreads();
  }
  __syncthreads();
#pragma unroll
  for (int e = 0; e < 8; e++) Xs[rbase + 8 * e][lane2] = acc[e];
  for (int l = t; l < 4096; l += 256) Lb[l >> 6][l & 63] = DG[(size_t)kb * 4096 + l];
  __syncthreads();
#pragma unroll
  for (int e = 0; e < 8; e++) {
    int i = rbase + 8 * e;
    double s = 0;
#pragma unroll 4
    for (int k = 0; k < 64; k++) s += Lb[k][i] * Xs[k][lane2];
    X[(size_t)(row0 + i) * ldx + c0 + lane2] = s;
  }
}

__global__ __launch_bounds__(256) void k_trsmb_g(const double* __restrict__ Lm, int lda,
                                                 double* __restrict__ X, int ldx,
                                                 const double* __restrict__ DG, int kb, int nkb) {
  __shared__ double Lb[64][64];
  __shared__ double Xs[64][33];
  int t = threadIdx.x;
  int c0 = blockIdx.x * 32;
  int lane2 = t & 31, rbase = t >> 5;
  int row0 = kb * 64;
  double acc[8];
#pragma unroll
  for (int e = 0; e < 8; e++) acc[e] = X[(size_t)(row0 + rbase + 8 * e) * ldx + c0 + lane2];
  for (int jb = kb + 1; jb < nkb; jb++) {
    for (int l = t; l < 4096; l += 256) { int r = l >> 6, c = l & 63; Lb[r][c] = Lm[(size_t)(jb * 64 + r) * lda + kb * 64 + c]; }
    for (int l = t; l < 2048; l += 256) { int k = l >> 5, c = l & 31; Xs[k][c] = X[(size_t)(jb * 64 + k) * ldx + c0 + c]; }
    __syncthreads();
#pragma unroll 4
    for (int k = 0; k < 64; k++) {
      double wv = Xs[k][lane2];
#pragma unroll
      for (int e = 0; e < 8; e++) acc[e] -= Lb[k][rbase + 8 * e] * wv;
    }
    __syncthreads();
  }
  __syncthreads();
#pragma unroll
  for (int e = 0; e < 8; e++) Xs[rbase + 8 * e][lane2] = acc[e];
  for (int l = t; l < 4096; l += 256) Lb[l >> 6][l & 63] = DG[(size_t)kb * 4096 + l];
  __syncthreads();
#pragma unroll
  for (int e = 0; e < 8; e++) {
    int i = rbase + 8 * e;
    double s = 0;
#pragma unroll 4
    for (int k = 0; k < 64; k++) s += Lb[i][k] * Xs[k][lane2];
    X[(size_t)(row0 + i) * ldx + c0 + lane2] = s;
  }
}

// ---------------- setup GEMMs (verified) ----------------
__global__ __launch_bounds__(256) void k_aqi(const float* __restrict__ Af, const double* __restrict__ Qi,
                                             double* __restrict__ AQi) {
  __shared__ double As[32][33], Bs[32][33];
  int i0 = blockIdx.x * 32, a0 = blockIdx.y * 32;
  int tx = threadIdx.x & 15, ty = threadIdx.x >> 4;
  double acc[2][2] = {};
  for (int k0 = 0; k0 < ND; k0 += 32) {
    for (int l = threadIdx.x; l < 1024; l += 256) {
      int r = l >> 5, c = l & 31;
      As[r][c] = (double)Af[(size_t)(a0 + r) * ND + k0 + c];
      Bs[r][c] = Qi[(size_t)(k0 + r) * ND + i0 + c];
    }
    __syncthreads();
#pragma unroll
    for (int k = 0; k < 32; k++) {
      double a0v = As[2 * ty][k], a1v = As[2 * ty + 1][k];
      double b0v = Bs[k][2 * tx], b1v = Bs[k][2 * tx + 1];
      acc[0][0] += a0v * b0v; acc[0][1] += a0v * b1v;
      acc[1][0] += a1v * b0v; acc[1][1] += a1v * b1v;
    }
    __syncthreads();
  }
  for (int da = 0; da < 2; da++)
    for (int db = 0; db < 2; db++)
      AQi[(size_t)(a0 + 2 * ty + da) * ND + i0 + 2 * tx + db] = acc[da][db];
}

__global__ __launch_bounds__(256) void k_sa(const double* __restrict__ AQi, const float* __restrict__ Af,
                                            double* __restrict__ SA) {
  __shared__ double As[32][33], Bs[32][33];
  int a0 = blockIdx.y * 32, b0 = blockIdx.x * 32;
  int tx = threadIdx.x & 15, ty = threadIdx.x >> 4;
  double acc[2][2] = {};
  for (int k0 = 0; k0 < ND; k0 += 32) {
    for (int l = threadIdx.x; l < 1024; l += 256) {
      int r = l >> 5, c = l & 31;
      As[r][c] = AQi[(size_t)(a0 + r) * ND + k0 + c];
      Bs[r][c] = (double)Af[(size_t)(b0 + r) * ND + k0 + c];
    }
    __syncthreads();
#pragma unroll
    for (int k = 0; k < 32; k++) {
      double a0v = As[2 * ty][k], a1v = As[2 * ty + 1][k];
      double b0v = Bs[2 * tx][k], b1v = Bs[2 * tx + 1][k];
      acc[0][0] += a0v * b0v; acc[0][1] += a0v * b1v;
      acc[1][0] += a1v * b0v; acc[1][1] += a1v * b1v;
    }
    __syncthreads();
  }
  for (int da = 0; da < 2; da++)
    for (int db = 0; db < 2; db++)
      SA[(size_t)(a0 + 2 * ty + da) * PE + b0 + 2 * tx + db] = acc[da][db];
}

__global__ __launch_bounds__(256) void k_xy(const double* __restrict__ AQi, const double* __restrict__ SAi,
                                            double* __restrict__ XY) {
  __shared__ double As[32][33], Bs[32][33];
  int b0 = blockIdx.x * 32, i0 = blockIdx.y * 32;
  int tx = threadIdx.x & 15, ty = threadIdx.x >> 4;
  double acc[2][2] = {};
  for (int k0 = 0; k0 < PE; k0 += 32) {
    for (int l = threadIdx.x; l < 1024; l += 256) {
      int r = l >> 5, c = l & 31;
      As[r][c] = AQi[(size_t)(k0 + r) * ND + i0 + c];
      Bs[r][c] = SAi[(size_t)(k0 + r) * PE + b0 + c];
    }
    __syncthreads();
#pragma unroll
    for (int k = 0; k < 32; k++) {
      double a0v = As[k][2 * ty], a1v = As[k][2 * ty + 1];
      double b0v = Bs[k][2 * tx], b1v = Bs[k][2 * tx + 1];
      acc[0][0] += a0v * b0v; acc[0][1] += a0v * b1v;
      acc[1][0] += a1v * b0v; acc[1][1] += a1v * b1v;
    }
    __syncthreads();
  }
  for (int da = 0; da < 2; da++)
    for (int db = 0; db < 2; db++)
      XY[(size_t)(i0 + 2 * ty + da) * PE + b0 + 2 * tx + db] = acc[da][db];
}

__global__ __launch_bounds__(256) void k_xx(const double* __restrict__ Qi, const double* __restrict__ XY,
                                            const double* __restrict__ AQi, double* __restrict__ XX) {
  __shared__ double As[32][33], Bs[32][33];
  int j0 = blockIdx.x * 32, i0 = blockIdx.y * 32;
  int tx = threadIdx.x & 15, ty = threadIdx.x >> 4;
  double acc[2][2] = {};
  for (int k0 = 0; k0 < PE; k0 += 32) {
    for (int l = threadIdx.x; l < 1024; l += 256) {
      int r = l >> 5, c = l & 31;
      As[r][c] = XY[(size_t)(i0 + r) * PE + k0 + c];
      Bs[r][c] = AQi[(size_t)(k0 + r) * ND + j0 + c];
    }
    __syncthreads();
#pragma unroll
    for (int k = 0; k < 32; k++) {
      double a0v = As[2 * ty][k], a1v = As[2 * ty + 1][k];
      double b0v = Bs[k][2 * tx], b1v = Bs[k][2 * tx + 1];
      acc[0][0] += a0v * b0v; acc[0][1] += a0v * b1v;
      acc[1][0] += a1v * b0v; acc[1][1] += a1v * b1v;
    }
    __syncthreads();
  }
  for (int da = 0; da < 2; da++)
    for (int db = 0; db < 2; db++) {
      int i = i0 + 2 * ty + da, j = j0 + 2 * tx + db;
      XX[(size_t)i * ND + j] = Qi[(size_t)i * ND + j] - acc[da][db];
    }
}

__global__ __launch_bounds__(256) void k_fk0x(const float* __restrict__ Gf, const double* __restrict__ XX,
                                              double* __restrict__ FK0x) {
  __shared__ double As[32][33], Bs[32][33];
  int j0 = blockIdx.x * 32, g0 = blockIdx.y * 32;
  int tx = threadIdx.x & 15, ty = threadIdx.x >> 4;
  double acc[2][2] = {};
  for (int k0 = 0; k0 < ND; k0 += 32) {
    for (int l = threadIdx.x; l < 1024; l += 256) {
      int r = l >> 5, c = l & 31;
      As[r][c] = (double)Gf[(size_t)(g0 + r) * ND + k0 + c];
      Bs[r][c] = XX[(size_t)(k0 + r) * ND + j0 + c];
    }
    __syncthreads();
#pragma unroll
    for (int k = 0; k < 32; k++) {
      double a0v = As[2 * ty][k], a1v = As[2 * ty + 1][k];
      double b0v = Bs[k][2 * tx], b1v = Bs[k][2 * tx + 1];
      acc[0][0] += a0v * b0v; acc[0][1] += a0v * b1v;
      acc[1][0] += a1v * b0v; acc[1][1] += a1v * b1v;
    }
    __syncthreads();
  }
  for (int da = 0; da < 2; da++)
    for (int db = 0; db < 2; db++)
      FK0x[(size_t)(g0 + 2 * ty + da) * ND + j0 + 2 * tx + db] = acc[da][db];
}

__global__ __launch_bounds__(256) void k_fk0y(const float* __restrict__ Gf, const double* __restrict__ XY,
                                              double* __restrict__ FK0y) {
  __shared__ double As[32][33], Bs[32][33];
  int b0 = blockIdx.x * 32, g0 = blockIdx.y * 32;
  int tx = threadIdx.x & 15, ty = threadIdx.x >> 4;
  double acc[2][2] = {};
  for (int k0 = 0; k0 < ND; k0 += 32) {
    for (int l = threadIdx.x; l < 1024; l += 256) {
      int r = l >> 5, c = l & 31;
      As[r][c] = (double)Gf[(size_t)(g0 + r) * ND + k0 + c];
      Bs[r][c] = XY[(size_t)(k0 + r) * PE + b0 + c];
    }
    __syncthreads();
#pragma unroll
    for (int k = 0; k < 32; k++) {
      double a0v = As[2 * ty][k], a1v = As[2 * ty + 1][k];
      double b0v = Bs[k][2 * tx], b1v = Bs[k][2 * tx + 1];
      acc[0][0] += a0v * b0v; acc[0][1] += a0v * b1v;
      acc[1][0] += a1v * b0v; acc[1][1] += a1v * b1v;
    }
    __syncthreads();
  }
  for (int da = 0; da < 2; da++)
    for (int db = 0; db < 2; db++)
      FK0y[(size_t)(g0 + 2 * ty + da) * PE + b0 + 2 * tx + db] = acc[da][db];
}

__global__ __launch_bounds__(256) void k_smat(const double* __restrict__ FK0x, const float* __restrict__ Gf,
                                              double* __restrict__ S) {
  __shared__ double As[32][33], Bs[32][33];
  int g0 = blockIdx.y * 32, h0 = blockIdx.x * 32;
  int tx = threadIdx.x & 15, ty = threadIdx.x >> 4;
  double acc[2][2] = {};
  for (int k0 = 0; k0 < ND; k0 += 32) {
    for (int l = threadIdx.x; l < 1024; l += 256) {
      int r = l >> 5, c = l & 31;
      As[r][c] = FK0x[(size_t)(g0 + r) * ND + k0 + c];
      Bs[r][c] = (double)Gf[(size_t)(h0 + r) * ND + k0 + c];
    }
    __syncthreads();
#pragma unroll
    for (int k = 0; k < 32; k++) {
      double a0v = As[2 * ty][k], a1v = As[2 * ty + 1][k];
      double b0v = Bs[2 * tx][k], b1v = Bs[2 * tx + 1][k];
      acc[0][0] += a0v * b0v; acc[0][1] += a0v * b1v;
      acc[1][0] += a1v * b0v; acc[1][1] += a1v * b1v;
    }
    __syncthreads();
  }
  for (int da = 0; da < 2; da++)
    for (int db = 0; db < 2; db++)
      S[(size_t)(g0 + 2 * ty + da) * MI + h0 + 2 * tx + db] = acc[da][db];
}

__global__ __launch_bounds__(256) void k_tr(const double* __restrict__ src, double* __restrict__ dst,
                                            int R, int Cc) {
  __shared__ double tile[32][33];
  int r0 = blockIdx.y * 32, c0 = blockIdx.x * 32;
  for (int l = threadIdx.x; l < 1024; l += 256) {
    int r = l >> 5, c = l & 31;
    tile[r][c] = src[(size_t)(r0 + r) * Cc + c0 + c];
  }
  __syncthreads();
  for (int l = threadIdx.x; l < 1024; l += 256) {
    int r = l >> 5, c = l & 31;
    dst[(size_t)(c0 + r) * R + r0 + c] = tile[c][r];
  }
}

// ---------------- per-iteration kernels ----------------
// A1: 0..255 rx; 256..447 rp(+uv,dinv)/ry; 448..511 M=S+diag(s/z)
__global__ __launch_bounds__(256) void k_A1(const double* __restrict__ Qd, const float* __restrict__ Gf,
                                            const float* __restrict__ Af, const float* __restrict__ GTf,
                                            const float* __restrict__ ATf, const double* __restrict__ qd,
                                            const double* __restrict__ bd, const double* __restrict__ hd,
                                            const double* __restrict__ xv, const double* __restrict__ sv,
                                            const double* __restrict__ zv, const double* __restrict__ yv,
                                            const double* __restrict__ scal, const double* __restrict__ S,
                                            double* __restrict__ rxv, double* __restrict__ rp,
                                            double* __restrict__ ry, double* __restrict__ uv,
                                            double* __restrict__ dinv, double* __restrict__ Mm) {
  int t = threadIdx.x, lane = t & 63;
  if (blockIdx.x < 256) {
    int wid = blockIdx.x * 4 + (t >> 6);
    double acc = 0;
    for (int k = lane; k < ND; k += 64) acc += Qd[(size_t)wid * ND + k] * xv[k];
    for (int k = lane; k < MI; k += 64) acc += (double)GTf[(size_t)wid * MI + k] * zv[k];
    for (int k = lane; k < PE; k += 64) acc += (double)ATf[(size_t)wid * PE + k] * yv[k];
    acc = wred(acc);
    if (lane == 0) rxv[wid] = acc + qd[wid];
  } else if (blockIdx.x < 448) {
    int wid = (blockIdx.x - 256) * 4 + (t >> 6);
    if (wid < MI) {
      double acc = 0;
      for (int c = lane; c < ND; c += 64) acc += (double)Gf[(size_t)wid * ND + c] * xv[c];
      acc = wred(acc);
      if (lane == 0) {
        double s0 = sv[wid], z0 = zv[wid];
        double rpv = acc + s0 - hd[wid];
        rp[wid] = rpv;
        double rc0 = s0 * z0 - SIG * scal[0];
        uv[wid] = (-rc0 + z0 * rpv) / s0;
        dinv[wid] = s0 / z0;
      }
    } else {
      int r = wid - MI;
      double acc = 0;
      for (int c = lane; c < ND; c += 64) acc += (double)Af[(size_t)r * ND + c] * xv[c];
      acc = wred(acc);
      if (lane == 0) ry[r] = acc - bd[r];
    }
  } else {
    int rbase = (blockIdx.x - 448) * 8;
    for (int rr = 0; rr < 8; ++rr) {
      int row = rbase + rr;
      for (int c = t; c < NM; c += 256) {
        double v = S[(size_t)row * MI + c];
        if (row == c) v += sv[row] / zv[row];
        Mm[(size_t)row * LDM + c] = v;
      }
    }
  }
}

// A2: 0..255 rhs1; 256..383 g0 -> Mm row NM; 384 diag0(M)->DGC[0]
__global__ __launch_bounds__(256) void k_A2(const double* __restrict__ rxv, const float* __restrict__ GTf,
                                            const double* __restrict__ uv, const double* __restrict__ ry,
                                            const double* __restrict__ S, const double* __restrict__ FK0x,
                                            const double* __restrict__ FK0y, double* __restrict__ rhs1,
                                            double* __restrict__ Mm, double* __restrict__ DGC) {
  __shared__ double sh2[6241];
  int t = threadIdx.x, lane = t & 63;
  if (blockIdx.x < 256) {
    int wid = blockIdx.x * 4 + (t >> 6);
    double acc = 0;
    for (int k = lane; k < MI; k += 64) acc += (double)GTf[(size_t)wid * MI + k] * uv[k];
    acc = wred(acc);
    if (lane == 0) rhs1[wid] = -(rxv[wid] + acc);
  } else if (blockIdx.x < 384) {
    int j = (blockIdx.x - 256) * 4 + (t >> 6);
    double acc = 0;
    for (int k = lane; k < ND; k += 64) acc += FK0x[(size_t)j * ND + k] * rxv[k];
    for (int m = lane; m < MI; m += 64) acc += S[(size_t)j * MI + m] * uv[m];
    for (int c = lane; c < PE; c += 64) acc += FK0y[(size_t)j * PE + c] * ry[c];
    acc = wred(acc);
    if (lane == 0) Mm[(size_t)NM * LDM + j] = -acc;
  } else {
    // diag0 of M (verified code, lda=LDM, kb=0)
    double* a = sh2;           // 4160
    double* invp = sh2 + 4160; // 2080
    for (int l = t; l < 4096; l += 256) { int r = l >> 6, c = l & 63; a[r * 65 + c] = Mm[(size_t)r * LDM + c]; }
    __syncthreads();
    if (t == 0) {
      double m = 0;
      for (int i = 0; i < 64; i++) m = fmax(m, fabs(a[i * 65 + i]));
      sh2[6240] = m * 1e-28 + 1e-280;
    }
    __syncthreads();
    double dfl = sh2[6240];
    for (int j = 0; j < 64; j++) {
      if (t == 0) a[j * 65 + j] = sqrt(fmax(a[j * 65 + j], dfl));
      __syncthreads();
      double piv = a[j * 65 + j];
      for (int r = j + 1 + t; r < 64; r += 256) a[r * 65 + j] /= piv;
      __syncthreads();
      int w = 63 - j;
      for (int l = t; l < w * w; l += 256) {
        int rr = j + 1 + l / w, cc = j + 1 + l % w;
        if (cc <= rr) a[rr * 65 + cc] -= a[rr * 65 + j] * a[cc * 65 + j];
      }
      __syncthreads();
    }
    if (t < 64) {
      int c = t;
      for (int i = c; i < 64; i++) {
        double v = (i == c) ? 1.0 : 0.0;
        for (int k = c; k < i; k++) v -= a[i * 65 + k] * invp[k * (k + 1) / 2 + c];
        invp[i * (i + 1) / 2 + c] = v / a[i * 65 + i];
      }
    }
    __syncthreads();
    for (int l = t; l < 4096; l += 256) {
      int r = l >> 6, c = l & 63;
      DGC[(size_t)c * 64 + r] = (c <= r) ? invp[r * (r + 1) / 2 + c] : 0.0;
    }
  }
}

// bwdupd: 8 fwd strips + backward solve (L from PL, inverses from DGC) + upd
__global__ __launch_bounds__(512) void k_bwdupd(const double* __restrict__ Mm, const double* __restrict__ PL,
                                                const double* __restrict__ DGC, const double* __restrict__ rp,
                                                const double* __restrict__ dinv, double* __restrict__ sv,
                                                double* __restrict__ zv, double* __restrict__ scal,
                                                double* __restrict__ solw) {
  __shared__ double DT[4096];
  __shared__ double g[NM];
  __shared__ double pseg[64];
  __shared__ double acc8[8][64];
  __shared__ double tmp[64];
  __shared__ double red[512];
  __shared__ double dsA[512];
  __shared__ double dzA[512];
  int t = threadIdx.x;
  for (int l = t; l < NM; l += 512) g[l] = Mm[(size_t)NM * LDM + l];
  for (int kbp = 0; kbp < 8; ++kbp) {
    __syncthreads();
    for (int l = t; l < 4096; l += 512) DT[l] = DGC[(size_t)kbp * 4096 + l];
    __syncthreads();
    if (t < 64) {
      double s = 0;
#pragma unroll
      for (int k = 0; k < 64; k++) s += g[kbp * 64 + k] * DT[k * 64 + t];
      pseg[t] = s;
    }
    __syncthreads();
    for (int c = (kbp + 1) * 64 + t; c < NM; c += 512) {
      double s = 0;
#pragma unroll
      for (int k = 0; k < 64; k++) s += pseg[k] * PL[(size_t)c * NM + kbp * 64 + k];
      g[c] -= s;
    }
    if (t < 64) g[kbp * 64 + t] = pseg[t];
  }
  int i8 = t & 63, p8 = t >> 6;
  for (int kb = 7; kb >= 0; --kb) {
    __syncthreads();
    for (int l = t; l < 4096; l += 512) DT[l] = DGC[(size_t)kb * 4096 + l];
    __syncthreads();
    int tr0 = kb * 64 + 64;
    double s = 0;
    for (int rr = p8; rr < NM - tr0; rr += 8)
      s += PL[(size_t)(tr0 + rr) * NM + kb * 64 + i8] * g[tr0 + rr];
    acc8[p8][i8] = s;
    __syncthreads();
    if (t < 64) {
      double v = g[kb * 64 + t];
#pragma unroll
      for (int p = 0; p < 8; p++) v -= acc8[p][t];
      tmp[t] = v;
    }
    __syncthreads();
    if (t < 64) {
      double v = 0;
#pragma unroll
      for (int l = 0; l < 64; l++) v += DT[t * 64 + l] * tmp[l];
      pseg[t] = v;
    }
    __syncthreads();
    if (t < 64) g[kb * 64 + t] = pseg[t];
  }
  __syncthreads();
  solw[t] = g[t];
  double mu = scal[0];
  double s0 = sv[t], z0 = zv[t];
  double ds = -rp[t] - dinv[t] * g[t];
  double rc0 = s0 * z0 - SIG * mu;
  double dz = (-rc0 - z0 * ds) / s0;
  dsA[t] = ds; dzA[t] = dz;
  double rs = (ds < 0.0) ? -s0 / ds : 1.0;
  double rz = (dz < 0.0) ? -z0 / dz : 1.0;
  red[t] = fmin(rs, rz);
  __syncthreads();
  for (int s2 = 256; s2; s2 >>= 1) { if (t < s2) red[t] = fmin(red[t], red[t + s2]); __syncthreads(); }
  double alpha = 0.99 * fmin(1.0, red[0]);
  if (!(alpha == alpha)) alpha = 0.0;
  double us = alpha * dsA[t], uz = alpha * dzA[t];
  if (isfinite(us)) sv[t] += us;
  if (isfinite(uz)) zv[t] += uz;
  __syncthreads();
  red[t] = sv[t] * zv[t];
  __syncthreads();
  for (int s2 = 256; s2; s2 >>= 1) { if (t < s2) red[t] += red[t + s2]; __syncthreads(); }
  if (t == 0) { scal[0] = red[0] / (double)MI; scal[1] = alpha; }
}

// C: dx rows + x update (0..255); dy rows + y update (256..319)
__global__ __launch_bounds__(256) void k_C(const double* __restrict__ XX, const double* __restrict__ XGT,
                                           const double* __restrict__ XY, const double* __restrict__ YXm,
                                           const double* __restrict__ YGT, const double* __restrict__ SAi,
                                           const double* __restrict__ rhs1, const double* __restrict__ solw,
                                           const double* __restrict__ ry, const double* __restrict__ scal,
                                           double* __restrict__ xv, double* __restrict__ yv) {
  int lane = threadIdx.x & 63;
  double al = scal[1];
  if (blockIdx.x < 256) {
    int wid = blockIdx.x * 4 + (int)(threadIdx.x >> 6);
    double acc = 0;
    for (int k = lane; k < ND; k += 64) acc += XX[(size_t)wid * ND + k] * rhs1[k];
    for (int m = lane; m < MI; m += 64) acc -= XGT[(size_t)wid * MI + m] * solw[m];
    for (int c = lane; c < PE; c += 64) acc -= XY[(size_t)wid * PE + c] * ry[c];
    acc = wred(acc);
    if (lane == 0) { double u = al * acc; if (isfinite(u)) xv[wid] += u; }
  } else {
    int r = (blockIdx.x - 256) * 4 + (int)(threadIdx.x >> 6);
    double acc = 0;
    for (int k = lane; k < ND; k += 64) acc += YXm[(size_t)r * ND + k] * rhs1[k];
    for (int m = lane; m < MI; m += 64) acc -= YGT[(size_t)r * MI + m] * solw[m];
    for (int c = lane; c < PE; c += 64) acc += SAi[(size_t)r * PE + c] * ry[c];
    acc = wred(acc);
    if (lane == 0) { double u = al * acc; if (isfinite(u)) yv[r] += u; }
  }
}

__global__ void k_out(const double* __restrict__ xv, float* __restrict__ out) {
  int i = blockIdx.x * blockDim.x + threadIdx.x;
  if (i < ND) out[i] = (float)xv[i];
}

__global__ void k_wsdiag(float mb, float* out) {
  int i = blockIdx.x * 256 + threadIdx.x;
  if (i < ND) out[i] = (i == 0 ? (65536.0f * (1.0f + mb)) : 0.0f);
}

extern "C" void kernel_launch(void* const* d_in, const int* in_sizes, int n_in,
                              void* d_out, int out_size, void* d_ws, size_t ws_size,
                              hipStream_t stream) {
  const float* Lf = (const float*)d_in[0];
  const float* qf = (const float*)d_in[1];
  const float* Gf = (const float*)d_in[2];
  const float* Af = (const float*)d_in[3];
  const float* bf = (const float*)d_in[4];
  const float* x0f = (const float*)d_in[5];
  const float* s0f = (const float*)d_in[6];

  double* w = (double*)d_ws;
  double* Qd  = w; w += (size_t)ND * ND;
  double* XX  = w; w += (size_t)ND * ND;          // also PLQ during setup
  double* R1  = w; w += (size_t)ND * ND;          // Qi -> XGT/YXm/YGT
  double* R2  = w; w += (size_t)ND * ND;          // LQ -> Mm(513xLDM)/FK0y/SAi/Smat
  double* XY  = w; w += (size_t)ND * PE;          // also PLA during setup
  double* FK0xReg = w; w += (size_t)MI * ND;      // AQi -> FK0x
  double* SA  = w; w += (size_t)PE * PE;
  double* PLi = w; w += (size_t)NM * NM;          // iteration chol L panels
  double* DGH = w; w += (size_t)16 * 4096;
  double* DGA = w; w += (size_t)4 * 4096;
  double* DGC = w; w += (size_t)8 * 4096;
  double* qd = w; w += ND;  double* bd = w; w += PE;  double* hd = w; w += MI;
  double* xv = w; w += ND;  double* sv = w; w += MI;  double* zv = w; w += MI;  double* yv = w; w += PE;
  double* rxv = w; w += ND; double* rp = w; w += MI;  double* ry = w; w += PE;
  double* uv = w; w += MI;  double* dinv = w; w += MI;
  double* rhs1 = w; w += ND; double* solw = w; w += NM;
  double* scal = w; w += 16;
  float* GTf = (float*)w;
  float* ATf = GTf + (size_t)ND * MI;
  char* wend = (char*)(ATf + (size_t)ND * PE);
  size_t need = (size_t)(wend - (char*)d_ws);
  if (ws_size < need) {
    k_wsdiag<<<4, 256, 0, stream>>>((float)(ws_size >> 20), (float*)d_out);
    return;
  }

  // region aliases
  double* Qi  = R1;
  double* XGT = R1;
  double* YXm = R1 + (size_t)ND * MI;
  double* YGT = R1 + (size_t)ND * MI + (size_t)PE * ND;
  double* LQ  = R2;
  double* Mm  = R2;
  double* FK0y = R2 + (size_t)(NM + 1) * LDM;
  double* SAi  = FK0y + (size_t)MI * PE;
  double* Smat = SAi + (size_t)PE * PE;
  double* AQi  = FK0xReg;
  double* FK0x = FK0xReg;
  double* PLQ  = XX;
  double* PLA  = XY;

  const size_t ldsFPS = (size_t)16640 * sizeof(double);

  // ---- setup ----
  k_prep<<<2048, 256, 0, stream>>>(Gf, Af, qf, bf, GTf, ATf, qd, bd, xv, sv, zv, yv, scal);
  k_h<<<128, 256, 0, stream>>>(Gf, x0f, s0f, hd);
  { dim3 g(32, 32); k_qbuild<<<g, 256, 0, stream>>>(Lf, Qd, LQ); }
  // chol(Q): diag0 + fps2 at kb=0,2,...,14 (last is tail)
  k_chol_diag_inv<<<1, 256, 0, stream>>>(LQ, ND, 0, DGH);
  for (int kb = 0; kb < 16; kb += 2) {
    int T = 16 - kb - 2;
    int grid = (T > 0) ? T * (T + 1) / 2 : 1;
    k_fps2<<<grid, 256, ldsFPS, stream>>>(LQ, ND, PLQ, ND, DGH, kb, 16);
  }
  for (int kb = 0; kb < 16; kb++)  k_trsmf_g<<<32, 256, 0, stream>>>(PLQ, ND, Qi, ND, DGH, kb);
  for (int kb = 15; kb >= 0; kb--) k_trsmb_g<<<32, 256, 0, stream>>>(PLQ, ND, Qi, ND, DGH, kb, 16);
  { dim3 g(32, 8);  k_aqi<<<g, 256, 0, stream>>>(Af, Qi, AQi); }
  { dim3 g(8, 8);   k_sa<<<g, 256, 0, stream>>>(AQi, Af, SA); }
  // chol(SA): diag0 + fps2 at kb=0 (full), kb=2 (tail)
  k_chol_diag_inv<<<1, 256, 0, stream>>>(SA, PE, 0, DGA);
  for (int kb = 0; kb < 4; kb += 2) {
    int T = 4 - kb - 2;
    int grid = (T > 0) ? T * (T + 1) / 2 : 1;
    k_fps2<<<grid, 256, ldsFPS, stream>>>(SA, PE, PLA, PE, DGA, kb, 4);
  }
  for (int kb = 0; kb < 4; kb++)  k_trsmf_g<<<8, 256, 0, stream>>>(PLA, PE, SAi, PE, DGA, kb);
  for (int kb = 3; kb >= 0; kb--) k_trsmb_g<<<8, 256, 0, stream>>>(PLA, PE, SAi, PE, DGA, kb, 4);
  { dim3 g(8, 32);  k_xy<<<g, 256, 0, stream>>>(AQi, SAi, XY); }
  { dim3 g(32, 32); k_xx<<<g, 256, 0, stream>>>(Qi, XY, AQi, XX); }
  { dim3 g(32, 16); k_fk0x<<<g, 256, 0, stream>>>(Gf, XX, FK0x); }
  { dim3 g(8, 16);  k_fk0y<<<g, 256, 0, stream>>>(Gf, XY, FK0y); }
  { dim3 g(16, 16); k_smat<<<g, 256, 0, stream>>>(FK0x, Gf, Smat); }
  { dim3 g(32, 16); k_tr<<<g, 256, 0, stream>>>(FK0x, XGT, MI, ND); }
  { dim3 g(8, 32);  k_tr<<<g, 256, 0, stream>>>(XY, YXm, ND, PE); }
  { dim3 g(8, 16);  k_tr<<<g, 256, 0, stream>>>(FK0y, YGT, MI, PE); }

  // ---- iterations: 8 dispatches each ----
  for (int it = 0; it < NITER; ++it) {
    k_A1<<<512, 256, 0, stream>>>(Qd, Gf, Af, GTf, ATf, qd, bd, hd, xv, sv, zv, yv, scal,
                                  Smat, rxv, rp, ry, uv, dinv, Mm);
    k_A2<<<385, 256, 0, stream>>>(rxv, GTf, uv, ry, Smat, FK0x, FK0y, rhs1, Mm, DGC);
    for (int kb = 0; kb < 8; kb += 2) {
      int T = 8 - kb - 2;
      int grid = (T > 0) ? T * (T + 1) / 2 : 1;
      k_fps2<<<grid, 256, ldsFPS, stream>>>(Mm, LDM, PLi, NM, DGC, kb, 8);
    }
    k_bwdupd<<<1, 512, 0, stream>>>(Mm, PLi, DGC, rp, dinv, sv, zv, scal, solw);
    k_C<<<320, 256, 0, stream>>>(XX, XGT, XY, YXm, YGT, SAi, rhs1, solw, ry, scal, xv, yv);
  }
  k_out<<<4, 256, 0, stream>>>(xv, (float*)d_out);
}

// Round 13
// 36190.189 us; speedup vs baseline: 1.1241x; 1.1241x over previous
//
#include <hip/hip_runtime.h>
#include <hip/hip_bf16.h>

// IPM QP solver, f64. R11 structure (verified, 12 dispatches/iter) with the
// 64x64 factor routine rewritten: 1-sync-per-column, idiv-free, deferred
// normalization (a_rc -= a_rj*a_cj/d). This was the hidden ~150us latency atom.
// Per iteration: A1(rx,rp+uv/dinv,ry) ; A2(rhs1, M=S+diag(s/z), g0->Mm row 512);
// diag0 + 7x k_fps (fused panel+syrk+next-diag); bwdupd; C. Output x as f32.

constexpr int ND = 1024;
constexpr int MI = 512;
constexpr int PE = 256;
constexpr int NM = 512;
constexpr int LDM = 520;
constexpr double EPSQ = 1e-4;
constexpr double SIG = 0.1;
constexpr int NITER = 25;

__device__ __forceinline__ double wred(double v) {
#pragma unroll
  for (int off = 32; off; off >>= 1) v += __shfl_down(v, off, 64);
  return v;
}

// ---------------- setup ----------------
__global__ void k_prep(const float* __restrict__ Gf, const float* __restrict__ Af,
                       const float* __restrict__ qf, const float* __restrict__ bf,
                       float* __restrict__ GTf, float* __restrict__ ATf,
                       double* __restrict__ qd, double* __restrict__ bd,
                       double* __restrict__ xv, double* __restrict__ sv,
                       double* __restrict__ zv, double* __restrict__ yv,
                       double* __restrict__ scal) {
  if (blockIdx.x == 0 && threadIdx.x == 0) { scal[0] = 1.0; scal[1] = 0.0; }
  for (size_t idx = (size_t)blockIdx.x * blockDim.x + threadIdx.x;
       idx < (size_t)MI * ND; idx += (size_t)gridDim.x * blockDim.x) {
    int k = (int)(idx >> 10), i = (int)(idx & 1023);
    GTf[(size_t)i * MI + k] = Gf[idx];
    if (idx < (size_t)PE * ND) ATf[(size_t)i * PE + k] = Af[idx];
    if (idx < ND) { qd[idx] = (double)qf[idx]; xv[idx] = 0.0; }
    if (idx < MI) { sv[idx] = 1.0; zv[idx] = 1.0; }
    if (idx < PE) { bd[idx] = (double)bf[idx]; yv[idx] = 0.0; }
  }
}

__global__ __launch_bounds__(256) void k_h(const float* __restrict__ Gf,
                                           const float* __restrict__ x0f,
                                           const float* __restrict__ s0f,
                                           double* __restrict__ hd) {
  int wid = blockIdx.x * 4 + (int)(threadIdx.x >> 6), lane = threadIdx.x & 63;
  if (wid >= MI) return;
  double acc = 0;
  for (int c = lane; c < ND; c += 64) acc += (double)Gf[(size_t)wid * ND + c] * (double)x0f[c];
  acc = wred(acc);
  if (lane == 0) hd[wid] = acc + (double)s0f[wid];
}

__global__ __launch_bounds__(256) void k_qbuild(const float* __restrict__ Lf,
                                                double* __restrict__ Qd, double* __restrict__ LQ) {
  __shared__ double As[32][33], Bs[32][33];
  int i0 = blockIdx.y * 32, j0 = blockIdx.x * 32;
  int tx = threadIdx.x & 15, ty = threadIdx.x >> 4;
  double acc[2][2] = {};
  int kmax = (i0 < j0 ? i0 : j0) + 32;
  for (int k0 = 0; k0 < kmax; k0 += 32) {
    for (int l = threadIdx.x; l < 1024; l += 256) {
      int r = l >> 5, c = l & 31;
      As[r][c] = (k0 + c <= i0 + r) ? (double)Lf[(size_t)(i0 + r) * ND + k0 + c] : 0.0;
      Bs[r][c] = (k0 + c <= j0 + r) ? (double)Lf[(size_t)(j0 + r) * ND + k0 + c] : 0.0;
    }
    __syncthreads();
#pragma unroll
    for (int k = 0; k < 32; k++) {
      double a0 = As[2 * ty][k], a1 = As[2 * ty + 1][k];
      double b0 = Bs[2 * tx][k], b1 = Bs[2 * tx + 1][k];
      acc[0][0] += a0 * b0; acc[0][1] += a0 * b1;
      acc[1][0] += a1 * b0; acc[1][1] += a1 * b1;
    }
    __syncthreads();
  }
  for (int da = 0; da < 2; da++)
    for (int db = 0; db < 2; db++) {
      int i = i0 + 2 * ty + da, j = j0 + 2 * tx + db;
      double v = acc[da][db] + (i == j ? EPSQ : 0.0);
      Qd[(size_t)i * ND + j] = v;
      LQ[(size_t)i * ND + j] = v;
    }
}

// diag factor + inverse: FAST version (1 sync/column, idiv-free, deferred norm)
__global__ __launch_bounds__(256) void k_chol_diag_inv(double* __restrict__ A, int lda, int kb,
                                                       double* __restrict__ DG) {
  __shared__ double a[4160];
  __shared__ double invp[2080];
  __shared__ double dtmp[64];
  int t = threadIdx.x;
  size_t base = (size_t)kb * 64;
  for (int l = t; l < 4096; l += 256) { int r = l >> 6, c = l & 63; a[r * 65 + c] = A[(base + r) * lda + base + c]; }
  __syncthreads();
  if (t == 0) {
    double m = 0;
    for (int i = 0; i < 64; i++) m = fmax(m, fabs(a[i * 65 + i]));
    a[4159] = m * 1e-28 + 1e-280;
  }
  __syncthreads();
  double dfl = a[4159];
  int rg = t >> 6, ln = t & 63;
  for (int j = 0; j < 64; ++j) {
    double invd = 1.0 / fmax(a[j * 65 + j], dfl);
    for (int r = j + 1 + rg; r < 64; r += 4) {
      int c = j + 1 + ln;
      if (c <= r) a[r * 65 + c] -= a[r * 65 + j] * a[c * 65 + j] * invd;
    }
    __syncthreads();
  }
  if (t < 64) dtmp[t] = 1.0 / sqrt(fmax(a[t * 65 + t], dfl));
  __syncthreads();
  for (int l = t; l < 4096; l += 256) { int r = l >> 6, c = l & 63; if (c <= r) a[r * 65 + c] *= dtmp[c]; }
  __syncthreads();
  for (int l = t; l < 4096; l += 256) { int r = l >> 6, c = l & 63; if (c <= r) A[(base + r) * lda + base + c] = a[r * 65 + c]; }
  if (t < 64) {
    int c = t;
    for (int i = c; i < 64; i++) {
      double v = (i == c) ? 1.0 : 0.0;
      for (int k = c; k < i; k++) v -= a[i * 65 + k] * invp[k * (k + 1) / 2 + c];
      invp[i * (i + 1) / 2 + c] = v / a[i * 65 + i];
    }
  }
  __syncthreads();
  for (int l = t; l < 4096; l += 256) {
    int r = l >> 6, c = l & 63;
    DG[(size_t)kb * 4096 + (size_t)c * 64 + r] = (c <= r) ? invp[r * (r + 1) / 2 + c] : 0.0;
  }
}

// Fused chol step kb: blocks (i,j), kb+1<=j<=i<nbk, recompute panels P_i,P_j
// from A col kb x DG[kb], update A(i,j) -= P_i P_j^T; (i,i) writes P_i to PL;
// block (kb+1,kb+1) factors its tile (FAST factor) -> DG[kb+1].
__global__ __launch_bounds__(256) void k_fps(double* __restrict__ A, int lda,
                                             double* __restrict__ PL, int ldp,
                                             double* __restrict__ DG, int kb) {
  extern __shared__ double sh[];
  double* DT = sh;            // 4096
  double* Bs = sh + 4096;     // 4160; later invp(2080)+dtmp(64) overlay
  double* Pi = sh + 8256;     // 4160
  double* Pj = sh + 12416;    // 4160; also 'a' for diag factor
  const int t = threadIdx.x;
  int idx = blockIdx.x;
  int bi = (int)((sqrtf(8.0f * (float)idx + 1.0f) - 1.0f) * 0.5f);
  while ((bi + 1) * (bi + 2) / 2 <= idx) ++bi;
  while (bi * (bi + 1) / 2 > idx) --bi;
  int bj = idx - bi * (bi + 1) / 2;
  const int ib = kb + 1 + bi, jb = kb + 1 + bj;
  const int tx = t & 15, ty = t >> 4;

  for (int l = t; l < 4096; l += 256) DT[l] = DG[(size_t)kb * 4096 + l];
  for (int l = t; l < 4096; l += 256) { int r = l >> 6, c = l & 63; Bs[r * 65 + c] = A[(size_t)(ib * 64 + r) * lda + kb * 64 + c]; }
  __syncthreads();
  // Pi = Bs * DT  (verified panel math)
  {
    double acc[4][4] = {};
    for (int k = 0; k < 64; ++k) {
      double b0 = Bs[ty * 65 + k], b1 = Bs[(ty + 16) * 65 + k];
      double b2 = Bs[(ty + 32) * 65 + k], b3 = Bs[(ty + 48) * 65 + k];
      double d0 = DT[k * 64 + tx], d1 = DT[k * 64 + tx + 16];
      double d2 = DT[k * 64 + tx + 32], d3 = DT[k * 64 + tx + 48];
      acc[0][0] += b0 * d0; acc[0][1] += b0 * d1; acc[0][2] += b0 * d2; acc[0][3] += b0 * d3;
      acc[1][0] += b1 * d0; acc[1][1] += b1 * d1; acc[1][2] += b1 * d2; acc[1][3] += b1 * d3;
      acc[2][0] += b2 * d0; acc[2][1] += b2 * d1; acc[2][2] += b2 * d2; acc[2][3] += b2 * d3;
      acc[3][0] += b3 * d0; acc[3][1] += b3 * d1; acc[3][2] += b3 * d2; acc[3][3] += b3 * d3;
    }
    __syncthreads();
    for (int e = 0; e < 4; ++e)
      for (int f = 0; f < 4; ++f) Pi[(ty + 16 * e) * 65 + tx + 16 * f] = acc[e][f];
  }
  __syncthreads();
  if (ib == jb) {
    for (int l = t; l < 4096; l += 256) {
      int r = l >> 6, c = l & 63;
      PL[(size_t)(ib * 64 + r) * ldp + kb * 64 + c] = Pi[r * 65 + c];
    }
    // a = A(tile) - Pi Pi^T
    double* a = Pj;
    {
      double acc[4][4] = {};
      for (int k = 0; k < 64; ++k) {
        double p0 = Pi[ty * 65 + k], p1 = Pi[(ty + 16) * 65 + k];
        double p2 = Pi[(ty + 32) * 65 + k], p3 = Pi[(ty + 48) * 65 + k];
        double q0 = Pi[tx * 65 + k], q1 = Pi[(tx + 16) * 65 + k];
        double q2 = Pi[(tx + 32) * 65 + k], q3 = Pi[(tx + 48) * 65 + k];
        acc[0][0] += p0 * q0; acc[0][1] += p0 * q1; acc[0][2] += p0 * q2; acc[0][3] += p0 * q3;
        acc[1][0] += p1 * q0; acc[1][1] += p1 * q1; acc[1][2] += p1 * q2; acc[1][3] += p1 * q3;
        acc[2][0] += p2 * q0; acc[2][1] += p2 * q1; acc[2][2] += p2 * q2; acc[2][3] += p2 * q3;
        acc[3][0] += p3 * q0; acc[3][1] += p3 * q1; acc[3][2] += p3 * q2; acc[3][3] += p3 * q3;
      }
      for (int e = 0; e < 4; ++e)
        for (int f = 0; f < 4; ++f) {
          int r = ty + 16 * e, c = tx + 16 * f;
          a[r * 65 + c] = A[(size_t)(ib * 64 + r) * lda + jb * 64 + c] - acc[e][f];
        }
    }
    __syncthreads();
    if (ib == kb + 1) {
      // FAST factor of 'a' -> DG[kb+1]
      if (t == 0) {
        double m = 0;
        for (int i = 0; i < 64; i++) m = fmax(m, fabs(a[i * 65 + i]));
        sh[16576] = m * 1e-28 + 1e-280;
      }
      __syncthreads();
      double dfl = sh[16576];
      int rg = t >> 6, ln = t & 63;
      for (int j = 0; j < 64; ++j) {
        double invd = 1.0 / fmax(a[j * 65 + j], dfl);
        for (int r = j + 1 + rg; r < 64; r += 4) {
          int c = j + 1 + ln;
          if (c <= r) a[r * 65 + c] -= a[r * 65 + j] * a[c * 65 + j] * invd;
        }
        __syncthreads();
      }
      double* invp = Bs;
      double* dtmp = Bs + 2080;
      if (t < 64) dtmp[t] = 1.0 / sqrt(fmax(a[t * 65 + t], dfl));
      __syncthreads();
      for (int l = t; l < 4096; l += 256) { int r = l >> 6, c = l & 63; if (c <= r) a[r * 65 + c] *= dtmp[c]; }
      __syncthreads();
      if (t < 64) {
        int c = t;
        for (int i = c; i < 64; ++i) {
          double v = (i == c) ? 1.0 : 0.0;
          for (int k = c; k < i; ++k) v -= a[i * 65 + k] * invp[k * (k + 1) / 2 + c];
          invp[i * (i + 1) / 2 + c] = v / a[i * 65 + i];
        }
      }
      __syncthreads();
      for (int l = t; l < 4096; l += 256) {
        int r = l >> 6, c = l & 63;
        DG[(size_t)(kb + 1) * 4096 + (size_t)c * 64 + r] = (c <= r) ? invp[r * (r + 1) / 2 + c] : 0.0;
      }
    } else {
      for (int l = t; l < 4096; l += 256) {
        int r = l >> 6, c = l & 63;
        A[(size_t)(ib * 64 + r) * lda + jb * 64 + c] = a[r * 65 + c];
      }
    }
  } else {
    for (int l = t; l < 4096; l += 256) { int r = l >> 6, c = l & 63; Bs[r * 65 + c] = A[(size_t)(jb * 64 + r) * lda + kb * 64 + c]; }
    __syncthreads();
    {
      double acc[4][4] = {};
      for (int k = 0; k < 64; ++k) {
        double b0 = Bs[ty * 65 + k], b1 = Bs[(ty + 16) * 65 + k];
        double b2 = Bs[(ty + 32) * 65 + k], b3 = Bs[(ty + 48) * 65 + k];
        double d0 = DT[k * 64 + tx], d1 = DT[k * 64 + tx + 16];
        double d2 = DT[k * 64 + tx + 32], d3 = DT[k * 64 + tx + 48];
        acc[0][0] += b0 * d0; acc[0][1] += b0 * d1; acc[0][2] += b0 * d2; acc[0][3] += b0 * d3;
        acc[1][0] += b1 * d0; acc[1][1] += b1 * d1; acc[1][2] += b1 * d2; acc[1][3] += b1 * d3;
        acc[2][0] += b2 * d0; acc[2][1] += b2 * d1; acc[2][2] += b2 * d2; acc[2][3] += b2 * d3;
        acc[3][0] += b3 * d0; acc[3][1] += b3 * d1; acc[3][2] += b3 * d2; acc[3][3] += b3 * d3;
      }
      __syncthreads();
      for (int e = 0; e < 4; ++e)
        for (int f = 0; f < 4; ++f) Pj[(ty + 16 * e) * 65 + tx + 16 * f] = acc[e][f];
    }
    __syncthreads();
    double acc[4][4] = {};
    for (int k = 0; k < 64; ++k) {
      double p0 = Pi[ty * 65 + k], p1 = Pi[(ty + 16) * 65 + k];
      double p2 = Pi[(ty + 32) * 65 + k], p3 = Pi[(ty + 48) * 65 + k];
      double q0 = Pj[tx * 65 + k], q1 = Pj[(tx + 16) * 65 + k];
      double q2 = Pj[(tx + 32) * 65 + k], q3 = Pj[(tx + 48) * 65 + k];
      acc[0][0] += p0 * q0; acc[0][1] += p0 * q1; acc[0][2] += p0 * q2; acc[0][3] += p0 * q3;
      acc[1][0] += p1 * q0; acc[1][1] += p1 * q1; acc[1][2] += p1 * q2; acc[1][3] += p1 * q3;
      acc[2][0] += p2 * q0; acc[2][1] += p2 * q1; acc[2][2] += p2 * q2; acc[2][3] += p2 * q3;
      acc[3][0] += p3 * q0; acc[3][1] += p3 * q1; acc[3][2] += p3 * q2; acc[3][3] += p3 * q3;
    }
    for (int e = 0; e < 4; ++e)
      for (int f = 0; f < 4; ++f) {
        int r = ty + 16 * e, c = tx + 16 * f;
        A[(size_t)(ib * 64 + r) * lda + jb * 64 + c] -= acc[e][f];
      }
  }
}

// generic trsm identity-RHS fwd / in-place bwd (verified)
__global__ __launch_bounds__(256) void k_trsmf_g(const double* __restrict__ Lm, int lda,
                                                 double* __restrict__ X, int ldx,
                                                 const double* __restrict__ DG, int kb) {
  __shared__ double Lb[64][64];
  __shared__ double Xs[64][33];
  int t = threadIdx.x;
  int c0 = blockIdx.x * 32;
  int lane2 = t & 31, rbase = t >> 5;
  int row0 = kb * 64;
  double acc[8];
#pragma unroll
  for (int e = 0; e < 8; e++) acc[e] = (row0 + rbase + 8 * e == c0 + lane2) ? 1.0 : 0.0;
  for (int jb = 0; jb < kb; jb++) {
    for (int l = t; l < 4096; l += 256) { int r = l >> 6, c = l & 63; Lb[r][c] = Lm[(size_t)(row0 + r) * lda + jb * 64 + c]; }
    for (int l = t; l < 2048; l += 256) { int k = l >> 5, c = l & 31; Xs[k][c] = X[(size_t)(jb * 64 + k) * ldx + c0 + c]; }
    __syncthreads();
#pragma unroll 4
    for (int k = 0; k < 64; k++) {
      double wv = Xs[k][lane2];
#pragma unroll
      for (int e = 0; e < 8; e++) acc[e] -= Lb[rbase + 8 * e][k] * wv;
    }
    __syncthreads();
  }
  __syncthreads();
#pragma unroll
  for (int e = 0; e < 8; e++) Xs[rbase + 8 * e][lane2] = acc[e];
  for (int l = t; l < 4096; l += 256) Lb[l >> 6][l & 63] = DG[(size_t)kb * 4096 + l];
  __syncthreads();
#pragma unroll
  for (int e = 0; e < 8; e++) {
    int i = rbase + 8 * e;
    double s = 0;
#pragma unroll 4
    for (int k = 0; k < 64; k++) s += Lb[k][i] * Xs[k][lane2];
    X[(size_t)(row0 + i) * ldx + c0 + lane2] = s;
  }
}

__global__ __launch_bounds__(256) void k_trsmb_g(const double* __restrict__ Lm, int lda,
                                                 double* __restrict__ X, int ldx,
                                                 const double* __restrict__ DG, int kb, int nkb) {
  __shared__ double Lb[64][64];
  __shared__ double Xs[64][33];
  int t = threadIdx.x;
  int c0 = blockIdx.x * 32;
  int lane2 = t & 31, rbase = t >> 5;
  int row0 = kb * 64;
  double acc[8];
#pragma unroll
  for (int e = 0; e < 8; e++) acc[e] = X[(size_t)(row0 + rbase + 8 * e) * ldx + c0 + lane2];
  for (int jb = kb + 1; jb < nkb; jb++) {
    for (int l = t; l < 4096; l += 256) { int r = l >> 6, c = l & 63; Lb[r][c] = Lm[(size_t)(jb * 64 + r) * lda + kb * 64 + c]; }
    for (int l = t; l < 2048; l += 256) { int k = l >> 5, c = l & 31; Xs[k][c] = X[(size_t)(jb * 64 + k) * ldx + c0 + c]; }
    __syncthreads();
#pragma unroll 4
    for (int k = 0; k < 64; k++) {
      double wv = Xs[k][lane2];
#pragma unroll
      for (int e = 0; e < 8; e++) acc[e] -= Lb[k][rbase + 8 * e] * wv;
    }
    __syncthreads();
  }
  __syncthreads();
#pragma unroll
  for (int e = 0; e < 8; e++) Xs[rbase + 8 * e][lane2] = acc[e];
  for (int l = t; l < 4096; l += 256) Lb[l >> 6][l & 63] = DG[(size_t)kb * 4096 + l];
  __syncthreads();
#pragma unroll
  for (int e = 0; e < 8; e++) {
    int i = rbase + 8 * e;
    double s = 0;
#pragma unroll 4
    for (int k = 0; k < 64; k++) s += Lb[i][k] * Xs[k][lane2];
    X[(size_t)(row0 + i) * ldx + c0 + lane2] = s;
  }
}

// ---------------- setup GEMMs (verified) ----------------
__global__ __launch_bounds__(256) void k_aqi(const float* __restrict__ Af, const double* __restrict__ Qi,
                                             double* __restrict__ AQi) {
  __shared__ double As[32][33], Bs[32][33];
  int i0 = blockIdx.x * 32, a0 = blockIdx.y * 32;
  int tx = threadIdx.x & 15, ty = threadIdx.x >> 4;
  double acc[2][2] = {};
  for (int k0 = 0; k0 < ND; k0 += 32) {
    for (int l = threadIdx.x; l < 1024; l += 256) {
      int r = l >> 5, c = l & 31;
      As[r][c] = (double)Af[(size_t)(a0 + r) * ND + k0 + c];
      Bs[r][c] = Qi[(size_t)(k0 + r) * ND + i0 + c];
    }
    __syncthreads();
#pragma unroll
    for (int k = 0; k < 32; k++) {
      double a0v = As[2 * ty][k], a1v = As[2 * ty + 1][k];
      double b0v = Bs[k][2 * tx], b1v = Bs[k][2 * tx + 1];
      acc[0][0] += a0v * b0v; acc[0][1] += a0v * b1v;
      acc[1][0] += a1v * b0v; acc[1][1] += a1v * b1v;
    }
    __syncthreads();
  }
  for (int da = 0; da < 2; da++)
    for (int db = 0; db < 2; db++)
      AQi[(size_t)(a0 + 2 * ty + da) * ND + i0 + 2 * tx + db] = acc[da][db];
}

__global__ __launch_bounds__(256) void k_sa(const double* __restrict__ AQi, const float* __restrict__ Af,
                                            double* __restrict__ SA) {
  __shared__ double As[32][33], Bs[32][33];
  int a0 = blockIdx.y * 32, b0 = blockIdx.x * 32;
  int tx = threadIdx.x & 15, ty = threadIdx.x >> 4;
  double acc[2][2] = {};
  for (int k0 = 0; k0 < ND; k0 += 32) {
    for (int l = threadIdx.x; l < 1024; l += 256) {
      int r = l >> 5, c = l & 31;
      As[r][c] = AQi[(size_t)(a0 + r) * ND + k0 + c];
      Bs[r][c] = (double)Af[(size_t)(b0 + r) * ND + k0 + c];
    }
    __syncthreads();
#pragma unroll
    for (int k = 0; k < 32; k++) {
      double a0v = As[2 * ty][k], a1v = As[2 * ty + 1][k];
      double b0v = Bs[2 * tx][k], b1v = Bs[2 * tx + 1][k];
      acc[0][0] += a0v * b0v; acc[0][1] += a0v * b1v;
      acc[1][0] += a1v * b0v; acc[1][1] += a1v * b1v;
    }
    __syncthreads();
  }
  for (int da = 0; da < 2; da++)
    for (int db = 0; db < 2; db++)
      SA[(size_t)(a0 + 2 * ty + da) * PE + b0 + 2 * tx + db] = acc[da][db];
}

__global__ __launch_bounds__(256) void k_xy(const double* __restrict__ AQi, const double* __restrict__ SAi,
                                            double* __restrict__ XY) {
  __shared__ double As[32][33], Bs[32][33];
  int b0 = blockIdx.x * 32, i0 = blockIdx.y * 32;
  int tx = threadIdx.x & 15, ty = threadIdx.x >> 4;
  double acc[2][2] = {};
  for (int k0 = 0; k0 < PE; k0 += 32) {
    for (int l = threadIdx.x; l < 1024; l += 256) {
      int r = l >> 5, c = l & 31;
      As[r][c] = AQi[(size_t)(k0 + r) * ND + i0 + c];
      Bs[r][c] = SAi[(size_t)(k0 + r) * PE + b0 + c];
    }
    __syncthreads();
#pragma unroll
    for (int k = 0; k < 32; k++) {
      double a0v = As[k][2 * ty], a1v = As[k][2 * ty + 1];
      double b0v = Bs[k][2 * tx], b1v = Bs[k][2 * tx + 1];
      acc[0][0] += a0v * b0v; acc[0][1] += a0v * b1v;
      acc[1][0] += a1v * b0v; acc[1][1] += a1v * b1v;
    }
    __syncthreads();
  }
  for (int da = 0; da < 2; da++)
    for (int db = 0; db < 2; db++)
      XY[(size_t)(i0 + 2 * ty + da) * PE + b0 + 2 * tx + db] = acc[da][db];
}

__global__ __launch_bounds__(256) void k_xx(const double* __restrict__ Qi, const double* __restrict__ XY,
                                            const double* __restrict__ AQi, double* __restrict__ XX) {
  __shared__ double As[32][33], Bs[32][33];
  int j0 = blockIdx.x * 32, i0 = blockIdx.y * 32;
  int tx = threadIdx.x & 15, ty = threadIdx.x >> 4;
  double acc[2][2] = {};
  for (int k0 = 0; k0 < PE; k0 += 32) {
    for (int l = threadIdx.x; l < 1024; l += 256) {
      int r = l >> 5, c = l & 31;
      As[r][c] = XY[(size_t)(i0 + r) * PE + k0 + c];
      Bs[r][c] = AQi[(size_t)(k0 + r) * ND + j0 + c];
    }
    __syncthreads();
#pragma unroll
    for (int k = 0; k < 32; k++) {
      double a0v = As[2 * ty][k], a1v = As[2 * ty + 1][k];
      double b0v = Bs[k][2 * tx], b1v = Bs[k][2 * tx + 1];
      acc[0][0] += a0v * b0v; acc[0][1] += a0v * b1v;
      acc[1][0] += a1v * b0v; acc[1][1] += a1v * b1v;
    }
    __syncthreads();
  }
  for (int da = 0; da < 2; da++)
    for (int db = 0; db < 2; db++) {
      int i = i0 + 2 * ty + da, j = j0 + 2 * tx + db;
      XX[(size_t)i * ND + j] = Qi[(size_t)i * ND + j] - acc[da][db];
    }
}

__global__ __launch_bounds__(256) void k_fk0x(const float* __restrict__ Gf, const double* __restrict__ XX,
                                              double* __restrict__ FK0x) {
  __shared__ double As[32][33], Bs[32][33];
  int j0 = blockIdx.x * 32, g0 = blockIdx.y * 32;
  int tx = threadIdx.x & 15, ty = threadIdx.x >> 4;
  double acc[2][2] = {};
  for (int k0 = 0; k0 < ND; k0 += 32) {
    for (int l = threadIdx.x; l < 1024; l += 256) {
      int r = l >> 5, c = l & 31;
      As[r][c] = (double)Gf[(size_t)(g0 + r) * ND + k0 + c];
      Bs[r][c] = XX[(size_t)(k0 + r) * ND + j0 + c];
    }
    __syncthreads();
#pragma unroll
    for (int k = 0; k < 32; k++) {
      double a0v = As[2 * ty][k], a1v = As[2 * ty + 1][k];
      double b0v = Bs[k][2 * tx], b1v = Bs[k][2 * tx + 1];
      acc[0][0] += a0v * b0v; acc[0][1] += a0v * b1v;
      acc[1][0] += a1v * b0v; acc[1][1] += a1v * b1v;
    }
    __syncthreads();
  }
  for (int da = 0; da < 2; da++)
    for (int db = 0; db < 2; db++)
      FK0x[(size_t)(g0 + 2 * ty + da) * ND + j0 + 2 * tx + db] = acc[da][db];
}

__global__ __launch_bounds__(256) void k_fk0y(const float* __restrict__ Gf, const double* __restrict__ XY,
                                              double* __restrict__ FK0y) {
  __shared__ double As[32][33], Bs[32][33];
  int b0 = blockIdx.x * 32, g0 = blockIdx.y * 32;
  int tx = threadIdx.x & 15, ty = threadIdx.x >> 4;
  double acc[2][2] = {};
  for (int k0 = 0; k0 < ND; k0 += 32) {
    for (int l = threadIdx.x; l < 1024; l += 256) {
      int r = l >> 5, c = l & 31;
      As[r][c] = (double)Gf[(size_t)(g0 + r) * ND + k0 + c];
      Bs[r][c] = XY[(size_t)(k0 + r) * PE + b0 + c];
    }
    __syncthreads();
#pragma unroll
    for (int k = 0; k < 32; k++) {
      double a0v = As[2 * ty][k], a1v = As[2 * ty + 1][k];
      double b0v = Bs[k][2 * tx], b1v = Bs[k][2 * tx + 1];
      acc[0][0] += a0v * b0v; acc[0][1] += a0v * b1v;
      acc[1][0] += a1v * b0v; acc[1][1] += a1v * b1v;
    }
    __syncthreads();
  }
  for (int da = 0; da < 2; da++)
    for (int db = 0; db < 2; db++)
      FK0y[(size_t)(g0 + 2 * ty + da) * PE + b0 + 2 * tx + db] = acc[da][db];
}

__global__ __launch_bounds__(256) void k_smat(const double* __restrict__ FK0x, const float* __restrict__ Gf,
                                              double* __restrict__ S) {
  __shared__ double As[32][33], Bs[32][33];
  int g0 = blockIdx.y * 32, h0 = blockIdx.x * 32;
  int tx = threadIdx.x & 15, ty = threadIdx.x >> 4;
  double acc[2][2] = {};
  for (int k0 = 0; k0 < ND; k0 += 32) {
    for (int l = threadIdx.x; l < 1024; l += 256) {
      int r = l >> 5, c = l & 31;
      As[r][c] = FK0x[(size_t)(g0 + r) * ND + k0 + c];
      Bs[r][c] = (double)Gf[(size_t)(h0 + r) * ND + k0 + c];
    }
    __syncthreads();
#pragma unroll
    for (int k = 0; k < 32; k++) {
      double a0v = As[2 * ty][k], a1v = As[2 * ty + 1][k];
      double b0v = Bs[2 * tx][k], b1v = Bs[2 * tx + 1][k];
      acc[0][0] += a0v * b0v; acc[0][1] += a0v * b1v;
      acc[1][0] += a1v * b0v; acc[1][1] += a1v * b1v;
    }
    __syncthreads();
  }
  for (int da = 0; da < 2; da++)
    for (int db = 0; db < 2; db++)
      S[(size_t)(g0 + 2 * ty + da) * MI + h0 + 2 * tx + db] = acc[da][db];
}

__global__ __launch_bounds__(256) void k_tr(const double* __restrict__ src, double* __restrict__ dst,
                                            int R, int Cc) {
  __shared__ double tile[32][33];
  int r0 = blockIdx.y * 32, c0 = blockIdx.x * 32;
  for (int l = threadIdx.x; l < 1024; l += 256) {
    int r = l >> 5, c = l & 31;
    tile[r][c] = src[(size_t)(r0 + r) * Cc + c0 + c];
  }
  __syncthreads();
  for (int l = threadIdx.x; l < 1024; l += 256) {
    int r = l >> 5, c = l & 31;
    dst[(size_t)(c0 + r) * R + r0 + c] = tile[c][r];
  }
}

// ---------------- per-iteration kernels ----------------
__global__ __launch_bounds__(256) void k_A1(const double* __restrict__ Qd, const float* __restrict__ Gf,
                                            const float* __restrict__ Af, const float* __restrict__ GTf,
                                            const float* __restrict__ ATf, const double* __restrict__ qd,
                                            const double* __restrict__ bd, const double* __restrict__ hd,
                                            const double* __restrict__ xv, const double* __restrict__ sv,
                                            const double* __restrict__ zv, const double* __restrict__ yv,
                                            const double* __restrict__ scal,
                                            double* __restrict__ rxv, double* __restrict__ rp,
                                            double* __restrict__ ry, double* __restrict__ uv,
                                            double* __restrict__ dinv) {
  int lane = threadIdx.x & 63;
  if (blockIdx.x < 256) {
    int wid = blockIdx.x * 4 + (int)(threadIdx.x >> 6);
    double acc = 0;
    for (int k = lane; k < ND; k += 64) acc += Qd[(size_t)wid * ND + k] * xv[k];
    for (int k = lane; k < MI; k += 64) acc += (double)GTf[(size_t)wid * MI + k] * zv[k];
    for (int k = lane; k < PE; k += 64) acc += (double)ATf[(size_t)wid * PE + k] * yv[k];
    acc = wred(acc);
    if (lane == 0) rxv[wid] = acc + qd[wid];
  } else {
    int wid = (blockIdx.x - 256) * 4 + (int)(threadIdx.x >> 6);
    if (wid < MI) {
      double acc = 0;
      for (int c = lane; c < ND; c += 64) acc += (double)Gf[(size_t)wid * ND + c] * xv[c];
      acc = wred(acc);
      if (lane == 0) {
        double s0 = sv[wid], z0 = zv[wid];
        double rpv = acc + s0 - hd[wid];
        rp[wid] = rpv;
        double rc0 = s0 * z0 - SIG * scal[0];
        uv[wid] = (-rc0 + z0 * rpv) / s0;
        dinv[wid] = s0 / z0;
      }
    } else {
      int r = wid - MI;
      double acc = 0;
      for (int c = lane; c < ND; c += 64) acc += (double)Af[(size_t)r * ND + c] * xv[c];
      acc = wred(acc);
      if (lane == 0) ry[r] = acc - bd[r];
    }
  }
}

// A2: blocks 0..255 rhs1; 256..319 M=S+diag(dinv); 320..447 g0 -> Mm row NM
__global__ __launch_bounds__(256) void k_A2(const double* __restrict__ rxv, const float* __restrict__ GTf,
                                            const double* __restrict__ uv, const double* __restrict__ dinv,
                                            const double* __restrict__ ry, const double* __restrict__ S,
                                            const double* __restrict__ FK0x, const double* __restrict__ FK0y,
                                            double* __restrict__ rhs1, double* __restrict__ Mm) {
  int t = threadIdx.x, lane = t & 63;
  if (blockIdx.x < 256) {
    int wid = blockIdx.x * 4 + (t >> 6);
    double acc = 0;
    for (int k = lane; k < MI; k += 64) acc += (double)GTf[(size_t)wid * MI + k] * uv[k];
    acc = wred(acc);
    if (lane == 0) rhs1[wid] = -(rxv[wid] + acc);
  } else if (blockIdx.x < 320) {
    int rbase = (blockIdx.x - 256) * 8;
    for (int rr = 0; rr < 8; ++rr) {
      int row = rbase + rr;
      for (int c = t; c < NM; c += 256) {
        double v = S[(size_t)row * MI + c];
        if (row == c) v += dinv[row];
        Mm[(size_t)row * LDM + c] = v;
      }
    }
  } else {
    int j = (blockIdx.x - 320) * 4 + (t >> 6);
    double acc = 0;
    for (int k = lane; k < ND; k += 64) acc += FK0x[(size_t)j * ND + k] * rxv[k];
    for (int m = lane; m < MI; m += 64) acc += S[(size_t)j * MI + m] * uv[m];
    for (int c = lane; c < PE; c += 64) acc += FK0y[(size_t)j * PE + c] * ry[c];
    acc = wred(acc);
    if (lane == 0) Mm[(size_t)NM * LDM + j] = -acc;
  }
}

// bwdupd: 8 fwd strips + backward solve + ds/dz/alpha + s,z,mu update (verified)
__global__ __launch_bounds__(512) void k_bwdupd(const double* __restrict__ Mm, const double* __restrict__ PL,
                                                const double* __restrict__ DGC, const double* __restrict__ rp,
                                                const double* __restrict__ dinv, double* __restrict__ sv,
                                                double* __restrict__ zv, double* __restrict__ scal,
                                                double* __restrict__ solw) {
  __shared__ double DT[4096];
  __shared__ double g[NM];
  __shared__ double pseg[64];
  __shared__ double acc8[8][64];
  __shared__ double tmp[64];
  __shared__ double red[512];
  __shared__ double dsA[512];
  __shared__ double dzA[512];
  int t = threadIdx.x;
  for (int l = t; l < NM; l += 512) g[l] = Mm[(size_t)NM * LDM + l];
  for (int kbp = 0; kbp < 8; ++kbp) {
    __syncthreads();
    for (int l = t; l < 4096; l += 512) DT[l] = DGC[(size_t)kbp * 4096 + l];
    __syncthreads();
    if (t < 64) {
      double s = 0;
#pragma unroll
      for (int k = 0; k < 64; k++) s += g[kbp * 64 + k] * DT[k * 64 + t];
      pseg[t] = s;
    }
    __syncthreads();
    for (int c = (kbp + 1) * 64 + t; c < NM; c += 512) {
      double s = 0;
#pragma unroll
      for (int k = 0; k < 64; k++) s += pseg[k] * PL[(size_t)c * NM + kbp * 64 + k];
      g[c] -= s;
    }
    if (t < 64) g[kbp * 64 + t] = pseg[t];
  }
  int i8 = t & 63, p8 = t >> 6;
  for (int kb = 7; kb >= 0; --kb) {
    __syncthreads();
    for (int l = t; l < 4096; l += 512) DT[l] = DGC[(size_t)kb * 4096 + l];
    __syncthreads();
    int tr0 = kb * 64 + 64;
    double s = 0;
    for (int rr = p8; rr < NM - tr0; rr += 8)
      s += PL[(size_t)(tr0 + rr) * NM + kb * 64 + i8] * g[tr0 + rr];
    acc8[p8][i8] = s;
    __syncthreads();
    if (t < 64) {
      double v = g[kb * 64 + t];
#pragma unroll
      for (int p = 0; p < 8; p++) v -= acc8[p][t];
      tmp[t] = v;
    }
    __syncthreads();
    if (t < 64) {
      double v = 0;
#pragma unroll
      for (int l = 0; l < 64; l++) v += DT[t * 64 + l] * tmp[l];
      pseg[t] = v;
    }
    __syncthreads();
    if (t < 64) g[kb * 64 + t] = pseg[t];
  }
  __syncthreads();
  solw[t] = g[t];
  double mu = scal[0];
  double s0 = sv[t], z0 = zv[t];
  double ds = -rp[t] - dinv[t] * g[t];
  double rc0 = s0 * z0 - SIG * mu;
  double dz = (-rc0 - z0 * ds) / s0;
  dsA[t] = ds; dzA[t] = dz;
  double rs = (ds < 0.0) ? -s0 / ds : 1.0;
  double rz = (dz < 0.0) ? -z0 / dz : 1.0;
  red[t] = fmin(rs, rz);
  __syncthreads();
  for (int s2 = 256; s2; s2 >>= 1) { if (t < s2) red[t] = fmin(red[t], red[t + s2]); __syncthreads(); }
  double alpha = 0.99 * fmin(1.0, red[0]);
  if (!(alpha == alpha)) alpha = 0.0;
  double us = alpha * dsA[t], uz = alpha * dzA[t];
  if (isfinite(us)) sv[t] += us;
  if (isfinite(uz)) zv[t] += uz;
  __syncthreads();
  red[t] = sv[t] * zv[t];
  __syncthreads();
  for (int s2 = 256; s2; s2 >>= 1) { if (t < s2) red[t] += red[t + s2]; __syncthreads(); }
  if (t == 0) { scal[0] = red[0] / (double)MI; scal[1] = alpha; }
}

// C: dx rows + x update (0..255); dy rows + y update (256..319)
__global__ __launch_bounds__(256) void k_C(const double* __restrict__ XX, const double* __restrict__ XGT,
                                           const double* __restrict__ XY, const double* __restrict__ YXm,
                                           const double* __restrict__ YGT, const double* __restrict__ SAi,
                                           const double* __restrict__ rhs1, const double* __restrict__ solw,
                                           const double* __restrict__ ry, const double* __restrict__ scal,
                                           double* __restrict__ xv, double* __restrict__ yv) {
  int lane = threadIdx.x & 63;
  double al = scal[1];
  if (blockIdx.x < 256) {
    int wid = blockIdx.x * 4 + (int)(threadIdx.x >> 6);
    double acc = 0;
    for (int k = lane; k < ND; k += 64) acc += XX[(size_t)wid * ND + k] * rhs1[k];
    for (int m = lane; m < MI; m += 64) acc -= XGT[(size_t)wid * MI + m] * solw[m];
    for (int c = lane; c < PE; c += 64) acc -= XY[(size_t)wid * PE + c] * ry[c];
    acc = wred(acc);
    if (lane == 0) { double u = al * acc; if (isfinite(u)) xv[wid] += u; }
  } else {
    int r = (blockIdx.x - 256) * 4 + (int)(threadIdx.x >> 6);
    double acc = 0;
    for (int k = lane; k < ND; k += 64) acc += YXm[(size_t)r * ND + k] * rhs1[k];
    for (int m = lane; m < MI; m += 64) acc -= YGT[(size_t)r * MI + m] * solw[m];
    for (int c = lane; c < PE; c += 64) acc += SAi[(size_t)r * PE + c] * ry[c];
    acc = wred(acc);
    if (lane == 0) { double u = al * acc; if (isfinite(u)) yv[r] += u; }
  }
}

__global__ void k_out(const double* __restrict__ xv, float* __restrict__ out) {
  int i = blockIdx.x * blockDim.x + threadIdx.x;
  if (i < ND) out[i] = (float)xv[i];
}

__global__ void k_wsdiag(float mb, float* out) {
  int i = blockIdx.x * 256 + threadIdx.x;
  if (i < ND) out[i] = (i == 0 ? (65536.0f * (1.0f + mb)) : 0.0f);
}

extern "C" void kernel_launch(void* const* d_in, const int* in_sizes, int n_in,
                              void* d_out, int out_size, void* d_ws, size_t ws_size,
                              hipStream_t stream) {
  const float* Lf = (const float*)d_in[0];
  const float* qf = (const float*)d_in[1];
  const float* Gf = (const float*)d_in[2];
  const float* Af = (const float*)d_in[3];
  const float* bf = (const float*)d_in[4];
  const float* x0f = (const float*)d_in[5];
  const float* s0f = (const float*)d_in[6];

  double* w = (double*)d_ws;
  double* Qd  = w; w += (size_t)ND * ND;
  double* XX  = w; w += (size_t)ND * ND;          // also PLQ during setup
  double* R1  = w; w += (size_t)ND * ND;          // Qi -> XGT/YXm/YGT
  double* R2  = w; w += (size_t)ND * ND;          // LQ -> Mm(513xLDM)/FK0y/SAi/Smat
  double* XY  = w; w += (size_t)ND * PE;          // also PLA during setup
  double* FK0xReg = w; w += (size_t)MI * ND;      // AQi -> FK0x
  double* SA  = w; w += (size_t)PE * PE;
  double* PLi = w; w += (size_t)NM * NM;          // iteration chol L panels
  double* DGH = w; w += (size_t)16 * 4096;
  double* DGA = w; w += (size_t)4 * 4096;
  double* DGC = w; w += (size_t)8 * 4096;
  double* qd = w; w += ND;  double* bd = w; w += PE;  double* hd = w; w += MI;
  double* xv = w; w += ND;  double* sv = w; w += MI;  double* zv = w; w += MI;  double* yv = w; w += PE;
  double* rxv = w; w += ND; double* rp = w; w += MI;  double* ry = w; w += PE;
  double* uv = w; w += MI;  double* dinv = w; w += MI;
  double* rhs1 = w; w += ND; double* solw = w; w += NM;
  double* scal = w; w += 16;
  float* GTf = (float*)w;
  float* ATf = GTf + (size_t)ND * MI;
  char* wend = (char*)(ATf + (size_t)ND * PE);
  size_t need = (size_t)(wend - (char*)d_ws);
  if (ws_size < need) {
    k_wsdiag<<<4, 256, 0, stream>>>((float)(ws_size >> 20), (float*)d_out);
    return;
  }

  // region aliases
  double* Qi  = R1;
  double* XGT = R1;
  double* YXm = R1 + (size_t)ND * MI;
  double* YGT = R1 + (size_t)ND * MI + (size_t)PE * ND;
  double* LQ  = R2;
  double* Mm  = R2;
  double* FK0y = R2 + (size_t)(NM + 1) * LDM;
  double* SAi  = FK0y + (size_t)MI * PE;
  double* Smat = SAi + (size_t)PE * PE;
  double* AQi  = FK0xReg;
  double* FK0x = FK0xReg;
  double* PLQ  = XX;
  double* PLA  = XY;

  const size_t ldsFPS = (size_t)16640 * sizeof(double);

  // ---- setup ----
  k_prep<<<2048, 256, 0, stream>>>(Gf, Af, qf, bf, GTf, ATf, qd, bd, xv, sv, zv, yv, scal);
  k_h<<<128, 256, 0, stream>>>(Gf, x0f, s0f, hd);
  { dim3 g(32, 32); k_qbuild<<<g, 256, 0, stream>>>(Lf, Qd, LQ); }
  k_chol_diag_inv<<<1, 256, 0, stream>>>(LQ, ND, 0, DGH);
  for (int kb = 0; kb < 15; kb++) {
    int nt = 15 - kb;
    k_fps<<<nt * (nt + 1) / 2, 256, ldsFPS, stream>>>(LQ, ND, PLQ, ND, DGH, kb);
  }
  for (int kb = 0; kb < 16; kb++)  k_trsmf_g<<<32, 256, 0, stream>>>(PLQ, ND, Qi, ND, DGH, kb);
  for (int kb = 15; kb >= 0; kb--) k_trsmb_g<<<32, 256, 0, stream>>>(PLQ, ND, Qi, ND, DGH, kb, 16);
  { dim3 g(32, 8);  k_aqi<<<g, 256, 0, stream>>>(Af, Qi, AQi); }
  { dim3 g(8, 8);   k_sa<<<g, 256, 0, stream>>>(AQi, Af, SA); }
  k_chol_diag_inv<<<1, 256, 0, stream>>>(SA, PE, 0, DGA);
  for (int kb = 0; kb < 3; kb++) {
    int nt = 3 - kb;
    k_fps<<<nt * (nt + 1) / 2, 256, ldsFPS, stream>>>(SA, PE, PLA, PE, DGA, kb);
  }
  for (int kb = 0; kb < 4; kb++)  k_trsmf_g<<<8, 256, 0, stream>>>(PLA, PE, SAi, PE, DGA, kb);
  for (int kb = 3; kb >= 0; kb--) k_trsmb_g<<<8, 256, 0, stream>>>(PLA, PE, SAi, PE, DGA, kb, 4);
  { dim3 g(8, 32);  k_xy<<<g, 256, 0, stream>>>(AQi, SAi, XY); }
  { dim3 g(32, 32); k_xx<<<g, 256, 0, stream>>>(Qi, XY, AQi, XX); }
  { dim3 g(32, 16); k_fk0x<<<g, 256, 0, stream>>>(Gf, XX, FK0x); }
  { dim3 g(8, 16);  k_fk0y<<<g, 256, 0, stream>>>(Gf, XY, FK0y); }
  { dim3 g(16, 16); k_smat<<<g, 256, 0, stream>>>(FK0x, Gf, Smat); }
  { dim3 g(32, 16); k_tr<<<g, 256, 0, stream>>>(FK0x, XGT, MI, ND); }
  { dim3 g(8, 32);  k_tr<<<g, 256, 0, stream>>>(XY, YXm, ND, PE); }
  { dim3 g(8, 16);  k_tr<<<g, 256, 0, stream>>>(FK0y, YGT, MI, PE); }

  // ---- iterations: 12 dispatches each ----
  for (int it = 0; it < NITER; ++it) {
    k_A1<<<448, 256, 0, stream>>>(Qd, Gf, Af, GTf, ATf, qd, bd, hd, xv, sv, zv, yv, scal,
                                  rxv, rp, ry, uv, dinv);
    k_A2<<<448, 256, 0, stream>>>(rxv, GTf, uv, dinv, ry, Smat, FK0x, FK0y, rhs1, Mm);
    k_chol_diag_inv<<<1, 256, 0, stream>>>(Mm, LDM, 0, DGC);
    for (int kb = 0; kb < 7; kb++) {
      int nt = 7 - kb;
      k_fps<<<nt * (nt + 1) / 2, 256, ldsFPS, stream>>>(Mm, LDM, PLi, NM, DGC, kb);
    }
    k_bwdupd<<<1, 512, 0, stream>>>(Mm, PLi, DGC, rp, dinv, sv, zv, scal, solw);
    k_C<<<320, 256, 0, stream>>>(XX, XGT, XY, YXm, YGT, SAi, rhs1, solw, ry, scal, xv, yv);
  }
  k_out<<<4, 256, 0, stream>>>(xv, (float*)d_out);
}